// Round 14
// baseline (388.020 us; speedup 1.0000x reference)
//
#include <hip/hip_runtime.h>
#include <stdint.h>

typedef unsigned short u16;
typedef unsigned int u32;
typedef __attribute__((ext_vector_type(4))) float f32x4;
typedef __attribute__((ext_vector_type(8))) __bf16 bf16x8;

#define N1T 4096
#define N2T 1024
#define DIMT 3072
#define KVD 2048
#define INN 2048
#define NH 16
#define DH 128

__device__ __forceinline__ u16 f2bf(float f) {
  u32 u = __builtin_bit_cast(u32, f);
  u = (u + 0x7fffu + ((u >> 16) & 1u)) >> 16;
  return (u16)u;
}

__device__ __forceinline__ float exp2_fast(float x) {
  return __builtin_amdgcn_exp2f(x);  // v_exp_f32 (native 2^x)
}

__device__ __forceinline__ u32 cvtpk(float lo, float hi) {
  u32 r;
  asm volatile("v_cvt_pk_bf16_f32 %0, %1, %2" : "=v"(r) : "v"(lo), "v"(hi));
  return r;
}

typedef __attribute__((address_space(1))) void gvoid_t;
typedef __attribute__((address_space(3))) void lvoid_t;

__device__ __forceinline__ void gload16(const void* g, void* l) {
  __builtin_amdgcn_global_load_lds((gvoid_t*)g, (lvoid_t*)l, 16, 0, 0);
}

// ---------------- LayerNorm (fp32 in) -> bf16 out ----------------
template<int NV>
__global__ __launch_bounds__(256) void ln_cast_kernel(
    const float* __restrict__ X, const float* __restrict__ G,
    const float* __restrict__ B, u16* __restrict__ out) {
  const int D = NV * 1024;
  const int t = threadIdx.x;
  const size_t row = blockIdx.x;
  const float4* xr = (const float4*)(X + row * D);
  float4 v[NV];
  float s = 0.f, ss = 0.f;
#pragma unroll
  for (int i = 0; i < NV; ++i) {
    v[i] = xr[i * 256 + t];
    s += v[i].x + v[i].y + v[i].z + v[i].w;
    ss += v[i].x * v[i].x + v[i].y * v[i].y + v[i].z * v[i].z + v[i].w * v[i].w;
  }
#pragma unroll
  for (int off = 32; off; off >>= 1) {
    s += __shfl_xor(s, off);
    ss += __shfl_xor(ss, off);
  }
  __shared__ float red[2][4];
  const int wave = t >> 6, lane = t & 63;
  if (lane == 0) { red[0][wave] = s; red[1][wave] = ss; }
  __syncthreads();
  s = red[0][0] + red[0][1] + red[0][2] + red[0][3];
  ss = red[1][0] + red[1][1] + red[1][2] + red[1][3];
  const float mu = s / D;
  const float rstd = rsqrtf(ss / D - mu * mu + 1e-5f);
  u16* orow = out + row * D;
#pragma unroll
  for (int i = 0; i < NV; ++i) {
    const int idx = (i * 256 + t) * 4;
    float4 g4 = *(const float4*)(G + idx);
    float4 b4 = *(const float4*)(B + idx);
    union { ushort4 v4; u16 h[4]; } pk;
    pk.h[0] = f2bf((v[i].x - mu) * rstd * g4.x + b4.x);
    pk.h[1] = f2bf((v[i].y - mu) * rstd * g4.y + b4.y);
    pk.h[2] = f2bf((v[i].z - mu) * rstd * g4.z + b4.z);
    pk.h[3] = f2bf((v[i].w - mu) * rstd * g4.w + b4.w);
    *(ushort4*)(orow + idx) = pk.v4;
  }
}

// ------------- transpose+cast: W fp32 [K][N] -> WT bf16 [N][K] -------------
__global__ __launch_bounds__(256) void tcast_kernel(
    const float* __restrict__ W, u16* __restrict__ WT, int K, int N) {
  __shared__ __align__(16) u16 tile[64][72];
  const int t = threadIdx.x;
  const int k0 = blockIdx.x * 64, n0 = blockIdx.y * 64;
#pragma unroll
  for (int i = 0; i < 4; ++i) {
    int idx = i * 256 + t;
    int r = idx >> 4, c = (idx & 15) << 2;
    float4 v = *(const float4*)(W + (size_t)(k0 + r) * N + n0 + c);
    union { ushort4 v4; u16 h[4]; } pk;
    pk.h[0] = f2bf(v.x); pk.h[1] = f2bf(v.y);
    pk.h[2] = f2bf(v.z); pk.h[3] = f2bf(v.w);
    *(ushort4*)&tile[r][c] = pk.v4;
  }
  __syncthreads();
#pragma unroll
  for (int j = 0; j < 2; ++j) {
    int cid = j * 256 + t;
    int nr = cid >> 3, kc = (cid & 7) << 3;
    union { uint4 v4; u16 h[8]; } pk;
#pragma unroll
    for (int jj = 0; jj < 8; ++jj) pk.h[jj] = tile[kc + jj][nr];
    *(uint4*)(WT + (size_t)(n0 + nr) * K + k0 + kc) = pk.v4;
  }
}

// ------------- GEMM 128x128 (m97-structure) -------------
template<int BF16OUT>
__global__ __launch_bounds__(256) void gemm_bt_kernel(
    const u16* __restrict__ A, size_t Az,
    const u16* __restrict__ Bt, size_t Btz,
    void* __restrict__ Cv, size_t Cz,
    int M, int N, int K, float scale) {
  __shared__ __align__(16) u16 As[128 * 64];
  __shared__ __align__(16) u16 Bs[128 * 64];
  A += (size_t)blockIdx.z * Az;
  Bt += (size_t)blockIdx.z * Btz;
  const int t = threadIdx.x, lane = t & 63, wave = t >> 6;
  const int m0 = blockIdx.x * 128, n0 = blockIdx.y * 128;
  const int wr = (wave >> 1) * 64, wc = (wave & 1) * 64;
  const int fr = lane & 15, fk = (lane >> 4) * 8;
  f32x4 acc[4][4];
#pragma unroll
  for (int i = 0; i < 4; ++i)
#pragma unroll
    for (int j = 0; j < 4; ++j)
#pragma unroll
      for (int r = 0; r < 4; ++r) acc[i][j][r] = 0.f;
  const int srow = t >> 3;
  const int scb = (t & 7) * 16;
  const int nk = K >> 6;
  for (int kt = 0; kt < nk; ++kt) {
    const char* Ab = (const char*)(A + (size_t)kt * 64);
    const char* Bb = (const char*)(Bt + (size_t)kt * 64);
#pragma unroll
    for (int r = 0; r < 4; ++r) {
      int row = srow + r * 32;
      gload16(Ab + (size_t)(m0 + row) * K * 2 + scb, (char*)As + t * 16 + r * 4096);
      gload16(Bb + (size_t)(n0 + row) * K * 2 + scb, (char*)Bs + t * 16 + r * 4096);
    }
    __syncthreads();
#pragma unroll
    for (int kk = 0; kk < 2; ++kk) {
      bf16x8 af[4], bfr[4];
#pragma unroll
      for (int i = 0; i < 4; ++i)
        af[i] = *(const bf16x8*)&As[(wr + i * 16 + fr) * 64 + kk * 32 + fk];
#pragma unroll
      for (int j = 0; j < 4; ++j)
        bfr[j] = *(const bf16x8*)&Bs[(wc + j * 16 + fr) * 64 + kk * 32 + fk];
#pragma unroll
      for (int i = 0; i < 4; ++i)
#pragma unroll
        for (int j = 0; j < 4; ++j)
          acc[i][j] = __builtin_amdgcn_mfma_f32_16x16x32_bf16(af[i], bfr[j], acc[i][j], 0, 0, 0);
    }
    __syncthreads();
  }
  const int cr = (lane >> 4) * 4, cc = lane & 15;
#pragma unroll
  for (int i = 0; i < 4; ++i)
#pragma unroll
    for (int j = 0; j < 4; ++j) {
      const int row = m0 + wr + i * 16 + cr;
      const int col = n0 + wc + j * 16 + cc;
      if (BF16OUT) {
        u16* C = (u16*)Cv + (size_t)blockIdx.z * Cz;
#pragma unroll
        for (int r = 0; r < 4; ++r) C[(size_t)(row + r) * N + col] = f2bf(acc[i][j][r] * scale);
      } else {
        float* C = (float*)Cv + (size_t)blockIdx.z * Cz;
#pragma unroll
        for (int r = 0; r < 4; ++r) C[(size_t)(row + r) * N + col] = acc[i][j][r];
      }
    }
}

// ------------- GEMM 256x256 body (single-buffered R7 schedule) -------------
__device__ __forceinline__ void stage_region(const u16* __restrict__ G, int ldk,
                                             int rowbase, int colbase,
                                             u16* lds, int t) {
  const int srow = t >> 2, sc = t & 3;
  const int swz = (srow >> 1) & 3;
#pragma unroll
  for (int r = 0; r < 2; ++r) {
    int row = r * 128 + srow;
    gload16(G + (size_t)(rowbase + row) * ldk + colbase + (sc ^ swz) * 8,
            (char*)lds + t * 16 + r * 8192);
  }
}

#define GPHASE(MSUB, KK, STAGE_STMT, RELOAD_B, VM0)                               \
  {                                                                               \
    STAGE_STMT;                                                                   \
    const u16* Aarr = (KK) ? A1s : A0s;                                           \
    _Pragma("unroll")                                                             \
    for (int fi = 0; fi < 4; ++fi) {                                              \
      int rowa = RM + (MSUB) * 64 + fi * 16 + fr;                                 \
      af[fi] = *(const bf16x8*)((const char*)Aarr + rowa * 64 +                   \
                                ((q ^ ((rowa >> 1) & 3)) * 16));                  \
    }                                                                             \
    if (RELOAD_B) {                                                               \
      const u16* Barr = (KK) ? B1s : B0s;                                         \
      _Pragma("unroll")                                                           \
      for (int j = 0; j < 4; ++j) {                                               \
        int rowb = RN + j * 16 + fr;                                              \
        bf[j] = *(const bf16x8*)((const char*)Barr + rowb * 64 +                  \
                                 ((q ^ ((rowb >> 1) & 3)) * 16));                 \
      }                                                                           \
    }                                                                             \
    if (VM0) { asm volatile("s_waitcnt vmcnt(0)" ::: "memory"); }                 \
    else     { asm volatile("s_waitcnt vmcnt(2)" ::: "memory"); }                 \
    __builtin_amdgcn_s_barrier();                                                 \
    asm volatile("s_waitcnt lgkmcnt(0)" ::: "memory");                            \
    __builtin_amdgcn_sched_barrier(0);                                            \
    __builtin_amdgcn_s_setprio(1);                                                \
    _Pragma("unroll")                                                             \
    for (int fi = 0; fi < 4; ++fi)                                                \
      _Pragma("unroll")                                                           \
      for (int j = 0; j < 4; ++j)                                                 \
        acc[(MSUB) * 4 + fi][j] = __builtin_amdgcn_mfma_f32_16x16x32_bf16(        \
            af[fi], bf[j], acc[(MSUB) * 4 + fi][j], 0, 0, 0);                     \
    __builtin_amdgcn_s_setprio(0);                                                \
    __builtin_amdgcn_s_barrier();                                                 \
  }

__device__ __forceinline__ void gemm256_body(
    const u16* __restrict__ A, const u16* __restrict__ Bt, u16* __restrict__ C,
    int N, int K, float scale, int bx, int by,
    u16* A0s, u16* A1s, u16* B0s, u16* B1s, int t) {
  const int lane = t & 63, wave = t >> 6;
  const int m0 = bx * 256, n0 = by * 256;
  const int RM = (wave >> 2) * 128, RN = (wave & 3) * 64;
  const int fr = lane & 15, q = lane >> 4;
  f32x4 acc[8][4];
#pragma unroll
  for (int i = 0; i < 8; ++i)
#pragma unroll
    for (int j = 0; j < 4; ++j)
#pragma unroll
      for (int r = 0; r < 4; ++r) acc[i][j][r] = 0.f;

  stage_region(Bt, K, n0, 0, B0s, t);
  stage_region(A, K, m0, 0, A0s, t);
  stage_region(Bt, K, n0, 32, B1s, t);
  asm volatile("s_waitcnt vmcnt(0)" ::: "memory");
  __builtin_amdgcn_s_barrier();

  const int nk = K >> 6;
#pragma unroll 1
  for (int kt = 0; kt < nk; ++kt) {
    const bool last = (kt == nk - 1);
    bf16x8 af[4], bf[4];
    GPHASE(0, 0, stage_region(A, K, m0, kt * 64 + 32, A1s, t), true, false)
    GPHASE(1, 0, if (!last) stage_region(Bt, K, n0, (kt + 1) * 64, B0s, t), false, last)
    GPHASE(1, 1, if (!last) stage_region(A, K, m0, (kt + 1) * 64, A0s, t), true, last)
    GPHASE(0, 1, if (!last) stage_region(Bt, K, n0, (kt + 1) * 64 + 32, B1s, t), false, last)
  }

  const int cr = (lane >> 4) * 4, cc = lane & 15;
#pragma unroll
  for (int i = 0; i < 8; ++i)
#pragma unroll
    for (int j = 0; j < 4; ++j) {
      const int row = m0 + RM + i * 16 + cr;
      const int col = n0 + RN + j * 16 + cc;
#pragma unroll
      for (int r = 0; r < 4; ++r) C[(size_t)(row + r) * N + col] = f2bf(acc[i][j][r] * scale);
    }
}

// merged k-GEMM (blocks 0..255) + vt-GEMM (blocks 256..511): balanced 2/CU
__global__ __launch_bounds__(512) void gemm256_dual_kernel(
    const u16* __restrict__ xn, const u16* __restrict__ WkvT,
    u16* __restrict__ kb, u16* __restrict__ vtb, float kscale) {
  __shared__ __align__(16) u16 A0s[256 * 32];
  __shared__ __align__(16) u16 A1s[256 * 32];
  __shared__ __align__(16) u16 B0s[256 * 32];
  __shared__ __align__(16) u16 B1s[256 * 32];
  const int t = threadIdx.x;
  const int bid = blockIdx.x;
  if (bid < 256) {
    gemm256_body(xn, WkvT, kb, 2048, 2048, kscale,
                 bid & 31, bid >> 5, A0s, A1s, B0s, B1s, t);
  } else {
    const int b2 = bid - 256;
    const int z = b2 >> 7, rem = b2 & 127;
    gemm256_body(WkvT + (size_t)2048 * 2048, xn + (size_t)z * 4096 * 2048,
                 vtb + (size_t)z * 2048 * 4096, 4096, 2048, 1.0f,
                 rem & 7, rem >> 3, A0s, A1s, B0s, B1s, t);
  }
}

// ------------- flash attention v4 (proven 86us): 32 q/wave, KV-split-2 -------------
// Q pre-scaled by scale*log2e; K by scale -> S in log2 domain.
// Grid 256 = 8 XCD x (4 bh x 4 qtile x 2 kvhalf). Block: 8 waves x 32 q
// (two 16-row B-frags sharing every kf/vf LDS read). LDS 128KB, 1 block/CU.
#define KVB 128
__device__ __forceinline__ int swz4(int row) {
  return ((row & 15) ^ (((row >> 4) & 1) << 2)) << 4;
}

__device__ __forceinline__ void stage_kv(const u16* Kbase, const u16* Vbase,
                                         int kv0, char* ks, char* vs, int t) {
  const int col = (t & 15) * 16;
#pragma unroll
  for (int r = 0; r < 4; ++r) {
    int row = (t >> 4) + r * 32;
    gload16((const char*)(Kbase + (size_t)(kv0 + row) * INN) + (col ^ swz4(row)),
            ks + t * 16 + r * 8192);
  }
#pragma unroll
  for (int r = 0; r < 4; ++r) {
    int row = (t >> 4) + r * 32;
    gload16((const char*)(Vbase + (size_t)row * N1T + kv0) + (col ^ swz4(row)),
            vs + t * 16 + r * 8192);
  }
}

__global__ __launch_bounds__(512, 2) void attn_kernel(
    const u16* __restrict__ Q, const u16* __restrict__ Kb,
    const u16* __restrict__ Vt, float* __restrict__ Opart,
    float* __restrict__ ml) {
  __shared__ __align__(16) u16 Ks[2][KVB * 128];   // [key][d]
  __shared__ __align__(16) u16 Vs[2][128 * KVB];   // [d][key]
  const int t = threadIdx.x, lane = t & 63, wave = t >> 6;
  const int bid = blockIdx.x;
  const int xcd = bid & 7, idx = bid >> 3;
  const int bh = (xcd << 2) | (idx >> 3);
  const int sub = idx & 7;
  const int qt = sub >> 1, half = sub & 1;
  const int b = bh >> 4, h = bh & 15;
  const int q0 = qt * 256 + wave * 32;
  const int fr = lane & 15, quad = lane >> 4;
  const int fk = quad * 8;
  const int frp = fr + (fr & 12);  // perm row offset

  bf16x8 qf0[4], qf1[4];
  {
    const u16* qr0 = Q + (size_t)(b * N2T + q0 + fr) * INN + h * DH;
    const u16* qr1 = Q + (size_t)(b * N2T + q0 + 16 + fr) * INN + h * DH;
#pragma unroll
    for (int c = 0; c < 4; ++c) {
      qf0[c] = *(const bf16x8*)(qr0 + c * 32 + fk);
      qf1[c] = *(const bf16x8*)(qr1 + c * 32 + fk);
    }
  }

  float m_run[2] = {-1e30f, -1e30f}, l_run[2] = {0.f, 0.f};
  f32x4 oT[2][8];
#pragma unroll
  for (int f = 0; f < 2; ++f)
#pragma unroll
    for (int i = 0; i < 8; ++i)
#pragma unroll
      for (int r = 0; r < 4; ++r) oT[f][i][r] = 0.f;

  const u16* Kbase = Kb + (size_t)(b * N1T) * INN + h * DH;
  const u16* Vbase = Vt + ((size_t)b * INN + h * DH) * N1T;
  const int kvb = half * 2048;

  const int NT = 2048 / KVB;  // 16 tiles
  int cur = 0;
  stage_kv(Kbase, Vbase, kvb, (char*)&Ks[0][0], (char*)&Vs[0][0], t);
  for (int tile = 0; tile < NT; ++tile) {
    if (tile + 1 < NT) {
      stage_kv(Kbase, Vbase, kvb + (tile + 1) * KVB, (char*)&Ks[cur ^ 1][0],
               (char*)&Vs[cur ^ 1][0], t);
      asm volatile("s_waitcnt vmcnt(8)" ::: "memory");
    } else {
      asm volatile("s_waitcnt vmcnt(0)" ::: "memory");
    }
    __builtin_amdgcn_s_barrier();
    __builtin_amdgcn_sched_barrier(0);
    const char* KsC = (const char*)&Ks[cur][0];
    const char* VsC = (const char*)&Vs[cur][0];

    // S^T = K_perm @ Q^T for both q-frags, kf read ONCE per (ni,c)
    f32x4 sT[2][8];
    __builtin_amdgcn_s_setprio(1);
#pragma unroll
    for (int ni = 0; ni < 8; ++ni) {
#pragma unroll
      for (int r = 0; r < 4; ++r) { sT[0][ni][r] = 0.f; sT[1][ni][r] = 0.f; }
      const int rowa = (ni >> 1) * 32 + (ni & 1) * 4 + frp;
      const int sz = swz4(rowa);
#pragma unroll
      for (int c = 0; c < 4; ++c) {
        bf16x8 kf = *(const bf16x8*)(KsC + rowa * 256 + ((c * 64 + quad * 16) ^ sz));
        sT[0][ni] = __builtin_amdgcn_mfma_f32_16x16x32_bf16(kf, qf0[c], sT[0][ni], 0, 0, 0);
        sT[1][ni] = __builtin_amdgcn_mfma_f32_16x16x32_bf16(kf, qf1[c], sT[1][ni], 0, 0, 0);
      }
    }
    __builtin_amdgcn_s_setprio(0);
    // online softmax in log2 domain, per q-frag
    union { u32 w[4]; bf16x8 v; } pa[2][4];
#pragma unroll
    for (int f = 0; f < 2; ++f) {
      float mt = sT[f][0][0];
#pragma unroll
      for (int ni = 0; ni < 8; ++ni)
#pragma unroll
        for (int r = 0; r < 4; ++r) mt = fmaxf(mt, sT[f][ni][r]);
      mt = fmaxf(mt, __shfl_xor(mt, 16));
      mt = fmaxf(mt, __shfl_xor(mt, 32));
      if (!__all(mt <= m_run[f] + 10.f)) {
        float mnew = fmaxf(m_run[f], mt);
        float alpha = exp2_fast(m_run[f] - mnew);
        m_run[f] = mnew;
        l_run[f] *= alpha;
#pragma unroll
        for (int i = 0; i < 8; ++i)
#pragma unroll
          for (int r = 0; r < 4; ++r) oT[f][i][r] *= alpha;
      }
      float lt = 0.f;
#pragma unroll
      for (int ni = 0; ni < 8; ++ni)
#pragma unroll
        for (int r = 0; r < 4; ++r) {
          sT[f][ni][r] = exp2_fast(sT[f][ni][r] - m_run[f]);
          lt += sT[f][ni][r];
        }
      lt += __shfl_xor(lt, 16);
      lt += __shfl_xor(lt, 32);
      l_run[f] += lt;
#pragma unroll
      for (int kk = 0; kk < 4; ++kk) {
        pa[f][kk].w[0] = cvtpk(sT[f][kk * 2][0], sT[f][kk * 2][1]);
        pa[f][kk].w[1] = cvtpk(sT[f][kk * 2][2], sT[f][kk * 2][3]);
        pa[f][kk].w[2] = cvtpk(sT[f][kk * 2 + 1][0], sT[f][kk * 2 + 1][1]);
        pa[f][kk].w[3] = cvtpk(sT[f][kk * 2 + 1][2], sT[f][kk * 2 + 1][3]);
      }
    }
    // O^T += V^T @ P for both q-frags, vf read ONCE per (ni2,kk)
    __builtin_amdgcn_s_setprio(1);
#pragma unroll
    for (int ni2 = 0; ni2 < 8; ++ni2) {
      const int rowv = ni2 * 16 + fr;
      const int sz = swz4(rowv);
#pragma unroll
      for (int kk = 0; kk < 4; ++kk) {
        bf16x8 vf = *(const bf16x8*)(VsC + rowv * 256 + ((kk * 64 + quad * 16) ^ sz));
        oT[0][ni2] = __builtin_amdgcn_mfma_f32_16x16x32_bf16(vf, pa[0][kk].v, oT[0][ni2], 0, 0, 0);
        oT[1][ni2] = __builtin_amdgcn_mfma_f32_16x16x32_bf16(vf, pa[1][kk].v, oT[1][ni2], 0, 0, 0);
      }
    }
    __builtin_amdgcn_s_setprio(0);
    __builtin_amdgcn_sched_barrier(0);
    __builtin_amdgcn_s_barrier();
    cur ^= 1;
  }
  // write unnormalized partials: Opart[half][(b*1024+q)*16+h][128 d]
#pragma unroll
  for (int f = 0; f < 2; ++f) {
    const size_t row = (size_t)(b * N2T + q0 + f * 16 + fr) * 16 + h;
    float* op = Opart + ((size_t)half * 32768 + row) * 128 + quad * 4;
#pragma unroll
    for (int ni2 = 0; ni2 < 8; ++ni2) {
      float4 v4 = {oT[f][ni2][0], oT[f][ni2][1], oT[f][ni2][2], oT[f][ni2][3]};
      *(float4*)(op + ni2 * 16) = v4;
    }
    if (quad == 0) {
      float2 v2 = {m_run[f], l_run[f]};
      *(float2*)(ml + ((size_t)half * 32768 + row) * 2) = v2;
    }
  }
}

// ------------- combine: merge 2 kv-half partials -> ab bf16 -------------
__global__ __launch_bounds__(256) void combine2_kernel(
    const float* __restrict__ Opart, const float* __restrict__ ml,
    u16* __restrict__ ab) {
  const int tid = blockIdx.x * 256 + threadIdx.x;  // 1,048,576 total
  const int row = tid >> 5;
  const int c = tid & 31;
  float2 ml1 = *(const float2*)(ml + (size_t)row * 2);
  float2 ml2 = *(const float2*)(ml + ((size_t)32768 + row) * 2);
  float m = fmaxf(ml1.x, ml2.x);
  float w1 = exp2_fast(ml1.x - m), w2 = exp2_fast(ml2.x - m);
  float inv = 1.0f / (w1 * ml1.y + w2 * ml2.y);
  float4 o1 = *(const float4*)(Opart + (size_t)row * 128 + c * 4);
  float4 o2 = *(const float4*)(Opart + ((size_t)32768 + row) * 128 + c * 4);
  union { ushort4 v4; u16 hh[4]; } pk;
  pk.hh[0] = f2bf((w1 * o1.x + w2 * o2.x) * inv);
  pk.hh[1] = f2bf((w1 * o1.y + w2 * o2.y) * inv);
  pk.hh[2] = f2bf((w1 * o1.z + w2 * o2.z) * inv);
  pk.hh[3] = f2bf((w1 * o1.w + w2 * o2.w) * inv);
  *(ushort4*)(ab + (size_t)(row >> 4) * 2048 + (row & 15) * 128 + c * 4) = pk.v4;
}

extern "C" void kernel_launch(void* const* d_in, const int* in_sizes, int n_in,
                              void* d_out, int out_size, void* d_ws, size_t ws_size,
                              hipStream_t stream) {
  const float* x = (const float*)d_in[0];
  const float* latents = (const float*)d_in[1];
  const float* ln1g = (const float*)d_in[2];
  const float* ln1b = (const float*)d_in[3];
  const float* ln2g = (const float*)d_in[4];
  const float* ln2b = (const float*)d_in[5];
  const float* Wq = (const float*)d_in[6];
  const float* Wkv = (const float*)d_in[7];
  const float* Wout = (const float*)d_in[8];

  char* w = (char*)d_ws;
  u16* xn = (u16*)w;   w += (size_t)8192 * 2048 * 2;   // 32.0 MB
  u16* lnb = (u16*)w;  w += (size_t)2048 * 3072 * 2;   // 12.6 MB
  u16* WqT = (u16*)w;  w += (size_t)2048 * 3072 * 2;
  u16* WkvT = (u16*)w; w += (size_t)4096 * 2048 * 2;
  u16* WoT = (u16*)w;  w += (size_t)3072 * 2048 * 2;
  u16* qb = (u16*)w;   w += (size_t)2048 * 2048 * 2;
  u16* kb = (u16*)w;   w += (size_t)8192 * 2048 * 2;
  u16* vtb = (u16*)w;  w += (size_t)2 * 2048 * 4096 * 2;
  u16* ab = (u16*)w;   w += (size_t)2048 * 2048 * 2;
  // attention partials OVERLAY xn+lnb (both dead before attn runs):
  // opart 2*32768*128*4B = 33.55 MB + ml 0.5 MB < 44.6 MB ✓
  float* opart = (float*)d_ws;
  float* mlbuf = (float*)((char*)d_ws + 33554432);

  dim3 blk(256);
  tcast_kernel<<<dim3(48, 32), blk, 0, stream>>>(Wq, WqT, 3072, 2048);
  tcast_kernel<<<dim3(32, 64), blk, 0, stream>>>(Wkv, WkvT, 2048, 4096);
  tcast_kernel<<<dim3(32, 48), blk, 0, stream>>>(Wout, WoT, 2048, 3072);
  ln_cast_kernel<2><<<8192, blk, 0, stream>>>(x, ln1g, ln1b, xn);
  ln_cast_kernel<3><<<2048, blk, 0, stream>>>(latents, ln2g, ln2b, lnb);

  const float scale = 0.29730177875068026f;            // 1/sqrt(sqrt(128))
  const float qscale = scale * 1.4426950408889634f;    // fold log2e into q
  gemm_bt_kernel<1><<<dim3(16, 16, 1), blk, 0, stream>>>(
      lnb, 0, WqT, 0, qb, 0, 2048, 2048, 3072, qscale);
  gemm256_dual_kernel<<<dim3(512), dim3(512), 0, stream>>>(
      xn, WkvT, kb, vtb, scale);
  attn_kernel<<<dim3(256), dim3(512), 0, stream>>>(qb, kb, vtb, opart, mlbuf);
  combine2_kernel<<<dim3(4096), blk, 0, stream>>>(opart, mlbuf, ab);
  gemm_bt_kernel<0><<<dim3(16, 24, 1), blk, 0, stream>>>(
      ab, 0, WoT, 0, d_out, 0, 2048, 3072, 2048, 1.0f);
}

// Round 15
// 385.379 us; speedup vs baseline: 1.0069x; 1.0069x over previous
//
#include <hip/hip_runtime.h>
#include <stdint.h>

typedef unsigned short u16;
typedef unsigned int u32;
typedef __attribute__((ext_vector_type(4))) float f32x4;
typedef __attribute__((ext_vector_type(8))) __bf16 bf16x8;

#define N1T 4096
#define N2T 1024
#define DIMT 3072
#define KVD 2048
#define INN 2048
#define NH 16
#define DH 128

__device__ __forceinline__ u16 f2bf(float f) {
  u32 u = __builtin_bit_cast(u32, f);
  u = (u + 0x7fffu + ((u >> 16) & 1u)) >> 16;
  return (u16)u;
}

__device__ __forceinline__ float exp2_fast(float x) {
  return __builtin_amdgcn_exp2f(x);  // v_exp_f32 (native 2^x)
}

__device__ __forceinline__ u32 cvtpk(float lo, float hi) {
  u32 r;
  asm volatile("v_cvt_pk_bf16_f32 %0, %1, %2" : "=v"(r) : "v"(lo), "v"(hi));
  return r;
}

typedef __attribute__((address_space(1))) void gvoid_t;
typedef __attribute__((address_space(3))) void lvoid_t;

__device__ __forceinline__ void gload16(const void* g, void* l) {
  __builtin_amdgcn_global_load_lds((gvoid_t*)g, (lvoid_t*)l, 16, 0, 0);
}

// ---------------- LayerNorm (fp32 in) -> bf16 out ----------------
template<int NV>
__global__ __launch_bounds__(256) void ln_cast_kernel(
    const float* __restrict__ X, const float* __restrict__ G,
    const float* __restrict__ B, u16* __restrict__ out) {
  const int D = NV * 1024;
  const int t = threadIdx.x;
  const size_t row = blockIdx.x;
  const float4* xr = (const float4*)(X + row * D);
  float4 v[NV];
  float s = 0.f, ss = 0.f;
#pragma unroll
  for (int i = 0; i < NV; ++i) {
    v[i] = xr[i * 256 + t];
    s += v[i].x + v[i].y + v[i].z + v[i].w;
    ss += v[i].x * v[i].x + v[i].y * v[i].y + v[i].z * v[i].z + v[i].w * v[i].w;
  }
#pragma unroll
  for (int off = 32; off; off >>= 1) {
    s += __shfl_xor(s, off);
    ss += __shfl_xor(ss, off);
  }
  __shared__ float red[2][4];
  const int wave = t >> 6, lane = t & 63;
  if (lane == 0) { red[0][wave] = s; red[1][wave] = ss; }
  __syncthreads();
  s = red[0][0] + red[0][1] + red[0][2] + red[0][3];
  ss = red[1][0] + red[1][1] + red[1][2] + red[1][3];
  const float mu = s / D;
  const float rstd = rsqrtf(ss / D - mu * mu + 1e-5f);
  u16* orow = out + row * D;
#pragma unroll
  for (int i = 0; i < NV; ++i) {
    const int idx = (i * 256 + t) * 4;
    float4 g4 = *(const float4*)(G + idx);
    float4 b4 = *(const float4*)(B + idx);
    union { ushort4 v4; u16 h[4]; } pk;
    pk.h[0] = f2bf((v[i].x - mu) * rstd * g4.x + b4.x);
    pk.h[1] = f2bf((v[i].y - mu) * rstd * g4.y + b4.y);
    pk.h[2] = f2bf((v[i].z - mu) * rstd * g4.z + b4.z);
    pk.h[3] = f2bf((v[i].w - mu) * rstd * g4.w + b4.w);
    *(ushort4*)(orow + idx) = pk.v4;
  }
}

// ------------- transpose+cast: W fp32 [K][N] -> WT bf16 [N][K] -------------
__global__ __launch_bounds__(256) void tcast_kernel(
    const float* __restrict__ W, u16* __restrict__ WT, int K, int N) {
  __shared__ __align__(16) u16 tile[64][72];
  const int t = threadIdx.x;
  const int k0 = blockIdx.x * 64, n0 = blockIdx.y * 64;
#pragma unroll
  for (int i = 0; i < 4; ++i) {
    int idx = i * 256 + t;
    int r = idx >> 4, c = (idx & 15) << 2;
    float4 v = *(const float4*)(W + (size_t)(k0 + r) * N + n0 + c);
    union { ushort4 v4; u16 h[4]; } pk;
    pk.h[0] = f2bf(v.x); pk.h[1] = f2bf(v.y);
    pk.h[2] = f2bf(v.z); pk.h[3] = f2bf(v.w);
    *(ushort4*)&tile[r][c] = pk.v4;
  }
  __syncthreads();
#pragma unroll
  for (int j = 0; j < 2; ++j) {
    int cid = j * 256 + t;
    int nr = cid >> 3, kc = (cid & 7) << 3;
    union { uint4 v4; u16 h[8]; } pk;
#pragma unroll
    for (int jj = 0; jj < 8; ++jj) pk.h[jj] = tile[kc + jj][nr];
    *(uint4*)(WT + (size_t)(n0 + nr) * K + k0 + kc) = pk.v4;
  }
}

// ------------- GEMM 128x128 (m97-structure) -------------
template<int BF16OUT>
__global__ __launch_bounds__(256) void gemm_bt_kernel(
    const u16* __restrict__ A, size_t Az,
    const u16* __restrict__ Bt, size_t Btz,
    void* __restrict__ Cv, size_t Cz,
    int M, int N, int K, float scale) {
  __shared__ __align__(16) u16 As[128 * 64];
  __shared__ __align__(16) u16 Bs[128 * 64];
  A += (size_t)blockIdx.z * Az;
  Bt += (size_t)blockIdx.z * Btz;
  const int t = threadIdx.x, lane = t & 63, wave = t >> 6;
  const int m0 = blockIdx.x * 128, n0 = blockIdx.y * 128;
  const int wr = (wave >> 1) * 64, wc = (wave & 1) * 64;
  const int fr = lane & 15, fk = (lane >> 4) * 8;
  f32x4 acc[4][4];
#pragma unroll
  for (int i = 0; i < 4; ++i)
#pragma unroll
    for (int j = 0; j < 4; ++j)
#pragma unroll
      for (int r = 0; r < 4; ++r) acc[i][j][r] = 0.f;
  const int srow = t >> 3;
  const int scb = (t & 7) * 16;
  const int nk = K >> 6;
  for (int kt = 0; kt < nk; ++kt) {
    const char* Ab = (const char*)(A + (size_t)kt * 64);
    const char* Bb = (const char*)(Bt + (size_t)kt * 64);
#pragma unroll
    for (int r = 0; r < 4; ++r) {
      int row = srow + r * 32;
      gload16(Ab + (size_t)(m0 + row) * K * 2 + scb, (char*)As + t * 16 + r * 4096);
      gload16(Bb + (size_t)(n0 + row) * K * 2 + scb, (char*)Bs + t * 16 + r * 4096);
    }
    __syncthreads();
#pragma unroll
    for (int kk = 0; kk < 2; ++kk) {
      bf16x8 af[4], bfr[4];
#pragma unroll
      for (int i = 0; i < 4; ++i)
        af[i] = *(const bf16x8*)&As[(wr + i * 16 + fr) * 64 + kk * 32 + fk];
#pragma unroll
      for (int j = 0; j < 4; ++j)
        bfr[j] = *(const bf16x8*)&Bs[(wc + j * 16 + fr) * 64 + kk * 32 + fk];
#pragma unroll
      for (int i = 0; i < 4; ++i)
#pragma unroll
        for (int j = 0; j < 4; ++j)
          acc[i][j] = __builtin_amdgcn_mfma_f32_16x16x32_bf16(af[i], bfr[j], acc[i][j], 0, 0, 0);
    }
    __syncthreads();
  }
  const int cr = (lane >> 4) * 4, cc = lane & 15;
#pragma unroll
  for (int i = 0; i < 4; ++i)
#pragma unroll
    for (int j = 0; j < 4; ++j) {
      const int row = m0 + wr + i * 16 + cr;
      const int col = n0 + wc + j * 16 + cc;
      if (BF16OUT) {
        u16* C = (u16*)Cv + (size_t)blockIdx.z * Cz;
#pragma unroll
        for (int r = 0; r < 4; ++r) C[(size_t)(row + r) * N + col] = f2bf(acc[i][j][r] * scale);
      } else {
        float* C = (float*)Cv + (size_t)blockIdx.z * Cz;
#pragma unroll
        for (int r = 0; r < 4; ++r) C[(size_t)(row + r) * N + col] = acc[i][j][r];
      }
    }
}

// ------------- GEMM 256x256 body (single-buffered R7 schedule) -------------
__device__ __forceinline__ void stage_region(const u16* __restrict__ G, int ldk,
                                             int rowbase, int colbase,
                                             u16* lds, int t) {
  const int srow = t >> 2, sc = t & 3;
  const int swz = (srow >> 1) & 3;
#pragma unroll
  for (int r = 0; r < 2; ++r) {
    int row = r * 128 + srow;
    gload16(G + (size_t)(rowbase + row) * ldk + colbase + (sc ^ swz) * 8,
            (char*)lds + t * 16 + r * 8192);
  }
}

#define GPHASE(MSUB, KK, STAGE_STMT, RELOAD_B, VM0)                               \
  {                                                                               \
    STAGE_STMT;                                                                   \
    const u16* Aarr = (KK) ? A1s : A0s;                                           \
    _Pragma("unroll")                                                             \
    for (int fi = 0; fi < 4; ++fi) {                                              \
      int rowa = RM + (MSUB) * 64 + fi * 16 + fr;                                 \
      af[fi] = *(const bf16x8*)((const char*)Aarr + rowa * 64 +                   \
                                ((q ^ ((rowa >> 1) & 3)) * 16));                  \
    }                                                                             \
    if (RELOAD_B) {                                                               \
      const u16* Barr = (KK) ? B1s : B0s;                                         \
      _Pragma("unroll")                                                           \
      for (int j = 0; j < 4; ++j) {                                               \
        int rowb = RN + j * 16 + fr;                                              \
        bf[j] = *(const bf16x8*)((const char*)Barr + rowb * 64 +                  \
                                 ((q ^ ((rowb >> 1) & 3)) * 16));                 \
      }                                                                           \
    }                                                                             \
    if (VM0) { asm volatile("s_waitcnt vmcnt(0)" ::: "memory"); }                 \
    else     { asm volatile("s_waitcnt vmcnt(2)" ::: "memory"); }                 \
    __builtin_amdgcn_s_barrier();                                                 \
    asm volatile("s_waitcnt lgkmcnt(0)" ::: "memory");                            \
    __builtin_amdgcn_sched_barrier(0);                                            \
    __builtin_amdgcn_s_setprio(1);                                                \
    _Pragma("unroll")                                                             \
    for (int fi = 0; fi < 4; ++fi)                                                \
      _Pragma("unroll")                                                           \
      for (int j = 0; j < 4; ++j)                                                 \
        acc[(MSUB) * 4 + fi][j] = __builtin_amdgcn_mfma_f32_16x16x32_bf16(        \
            af[fi], bf[j], acc[(MSUB) * 4 + fi][j], 0, 0, 0);                     \
    __builtin_amdgcn_s_setprio(0);                                                \
    __builtin_amdgcn_s_barrier();                                                 \
  }

__device__ __forceinline__ void gemm256_body(
    const u16* __restrict__ A, const u16* __restrict__ Bt, u16* __restrict__ C,
    int N, int K, float scale, int bx, int by,
    u16* A0s, u16* A1s, u16* B0s, u16* B1s, int t) {
  const int lane = t & 63, wave = t >> 6;
  const int m0 = bx * 256, n0 = by * 256;
  const int RM = (wave >> 2) * 128, RN = (wave & 3) * 64;
  const int fr = lane & 15, q = lane >> 4;
  f32x4 acc[8][4];
#pragma unroll
  for (int i = 0; i < 8; ++i)
#pragma unroll
    for (int j = 0; j < 4; ++j)
#pragma unroll
      for (int r = 0; r < 4; ++r) acc[i][j][r] = 0.f;

  stage_region(Bt, K, n0, 0, B0s, t);
  stage_region(A, K, m0, 0, A0s, t);
  stage_region(Bt, K, n0, 32, B1s, t);
  asm volatile("s_waitcnt vmcnt(0)" ::: "memory");
  __builtin_amdgcn_s_barrier();

  const int nk = K >> 6;
#pragma unroll 1
  for (int kt = 0; kt < nk; ++kt) {
    const bool last = (kt == nk - 1);
    bf16x8 af[4], bf[4];
    GPHASE(0, 0, stage_region(A, K, m0, kt * 64 + 32, A1s, t), true, false)
    GPHASE(1, 0, if (!last) stage_region(Bt, K, n0, (kt + 1) * 64, B0s, t), false, last)
    GPHASE(1, 1, if (!last) stage_region(A, K, m0, (kt + 1) * 64, A0s, t), true, last)
    GPHASE(0, 1, if (!last) stage_region(Bt, K, n0, (kt + 1) * 64 + 32, B1s, t), false, last)
  }

  const int cr = (lane >> 4) * 4, cc = lane & 15;
#pragma unroll
  for (int i = 0; i < 8; ++i)
#pragma unroll
    for (int j = 0; j < 4; ++j) {
      const int row = m0 + RM + i * 16 + cr;
      const int col = n0 + RN + j * 16 + cc;
#pragma unroll
      for (int r = 0; r < 4; ++r) C[(size_t)(row + r) * N + col] = f2bf(acc[i][j][r] * scale);
    }
}

// merged k-GEMM + vt-GEMM with XCD-aware block placement (T1).
// HW round-robins blocks to XCDs by dispatch index (bid%8). Remap
// l = (bid%8)*64 + bid/8 (bijective) so XCD x owns logical blocks
// [x*64, x*64+64): k-GEMM lands on XCDs 0-3, vt-GEMM on XCDs 4-7
// (equal FLOPs -> balanced). Within an XCD the 64 blocks cover an
// 8bx x 8by panel square: per-kt working set = 8 A-slices + 8 B-slices
// x 32KB = 512KB << 4MB L2, so stage loads become L2 hits (~200-300cy),
// matching the pipeline's short prefetch distance (R7 diagnosis).
__global__ __launch_bounds__(512) void gemm256_dual_kernel(
    const u16* __restrict__ xn, const u16* __restrict__ WkvT,
    u16* __restrict__ kb, u16* __restrict__ vtb, float kscale) {
  __shared__ __align__(16) u16 A0s[256 * 32];
  __shared__ __align__(16) u16 A1s[256 * 32];
  __shared__ __align__(16) u16 B0s[256 * 32];
  __shared__ __align__(16) u16 B1s[256 * 32];
  const int t = threadIdx.x;
  const int bid = blockIdx.x;
  const int l = (bid & 7) * 64 + (bid >> 3);  // bijective XCD-chunk remap
  if (l < 256) {
    // k = xn @ Wk : M=8192 (32 bx), N=2048 (8 by), K=2048.
    // XCD group g owns bx in [8g,8g+8), all 8 by.
    const int g = l >> 6, r = l & 63;
    gemm256_body(xn, WkvT, kb, 2048, 2048, kscale,
                 g * 8 + (r & 7), r >> 3, A0s, A1s, B0s, B1s, t);
  } else {
    // v^T = Wv^T @ xn^T per batch: M=2048 (8 bx), N=4096 (16 by), K=2048.
    // XCD group g owns batch z=g>>1, by in [(g&1)*8, +8), all 8 bx.
    const int l2 = l - 256;
    const int g = l2 >> 6, r = l2 & 63;
    const int z = g >> 1;
    gemm256_body(WkvT + (size_t)2048 * 2048, xn + (size_t)z * 4096 * 2048,
                 vtb + (size_t)z * 2048 * 4096, 4096, 2048, 1.0f,
                 r & 7, (g & 1) * 8 + (r >> 3), A0s, A1s, B0s, B1s, t);
  }
}

// ------------- flash attention v4 (proven 86us): 32 q/wave, KV-split-2 -------------
#define KVB 128
__device__ __forceinline__ int swz4(int row) {
  return ((row & 15) ^ (((row >> 4) & 1) << 2)) << 4;
}

__device__ __forceinline__ void stage_kv(const u16* Kbase, const u16* Vbase,
                                         int kv0, char* ks, char* vs, int t) {
  const int col = (t & 15) * 16;
#pragma unroll
  for (int r = 0; r < 4; ++r) {
    int row = (t >> 4) + r * 32;
    gload16((const char*)(Kbase + (size_t)(kv0 + row) * INN) + (col ^ swz4(row)),
            ks + t * 16 + r * 8192);
  }
#pragma unroll
  for (int r = 0; r < 4; ++r) {
    int row = (t >> 4) + r * 32;
    gload16((const char*)(Vbase + (size_t)row * N1T + kv0) + (col ^ swz4(row)),
            vs + t * 16 + r * 8192);
  }
}

__global__ __launch_bounds__(512, 2) void attn_kernel(
    const u16* __restrict__ Q, const u16* __restrict__ Kb,
    const u16* __restrict__ Vt, float* __restrict__ Opart,
    float* __restrict__ ml) {
  __shared__ __align__(16) u16 Ks[2][KVB * 128];   // [key][d]
  __shared__ __align__(16) u16 Vs[2][128 * KVB];   // [d][key]
  const int t = threadIdx.x, lane = t & 63, wave = t >> 6;
  const int bid = blockIdx.x;
  const int xcd = bid & 7, idx = bid >> 3;
  const int bh = (xcd << 2) | (idx >> 3);
  const int sub = idx & 7;
  const int qt = sub >> 1, half = sub & 1;
  const int b = bh >> 4, h = bh & 15;
  const int q0 = qt * 256 + wave * 32;
  const int fr = lane & 15, quad = lane >> 4;
  const int fk = quad * 8;
  const int frp = fr + (fr & 12);  // perm row offset

  bf16x8 qf0[4], qf1[4];
  {
    const u16* qr0 = Q + (size_t)(b * N2T + q0 + fr) * INN + h * DH;
    const u16* qr1 = Q + (size_t)(b * N2T + q0 + 16 + fr) * INN + h * DH;
#pragma unroll
    for (int c = 0; c < 4; ++c) {
      qf0[c] = *(const bf16x8*)(qr0 + c * 32 + fk);
      qf1[c] = *(const bf16x8*)(qr1 + c * 32 + fk);
    }
  }

  float m_run[2] = {-1e30f, -1e30f}, l_run[2] = {0.f, 0.f};
  f32x4 oT[2][8];
#pragma unroll
  for (int f = 0; f < 2; ++f)
#pragma unroll
    for (int i = 0; i < 8; ++i)
#pragma unroll
      for (int r = 0; r < 4; ++r) oT[f][i][r] = 0.f;

  const u16* Kbase = Kb + (size_t)(b * N1T) * INN + h * DH;
  const u16* Vbase = Vt + ((size_t)b * INN + h * DH) * N1T;
  const int kvb = half * 2048;

  const int NT = 2048 / KVB;  // 16 tiles
  int cur = 0;
  stage_kv(Kbase, Vbase, kvb, (char*)&Ks[0][0], (char*)&Vs[0][0], t);
  for (int tile = 0; tile < NT; ++tile) {
    if (tile + 1 < NT) {
      stage_kv(Kbase, Vbase, kvb + (tile + 1) * KVB, (char*)&Ks[cur ^ 1][0],
               (char*)&Vs[cur ^ 1][0], t);
      asm volatile("s_waitcnt vmcnt(8)" ::: "memory");
    } else {
      asm volatile("s_waitcnt vmcnt(0)" ::: "memory");
    }
    __builtin_amdgcn_s_barrier();
    __builtin_amdgcn_sched_barrier(0);
    const char* KsC = (const char*)&Ks[cur][0];
    const char* VsC = (const char*)&Vs[cur][0];

    // S^T = K_perm @ Q^T for both q-frags, kf read ONCE per (ni,c)
    f32x4 sT[2][8];
    __builtin_amdgcn_s_setprio(1);
#pragma unroll
    for (int ni = 0; ni < 8; ++ni) {
#pragma unroll
      for (int r = 0; r < 4; ++r) { sT[0][ni][r] = 0.f; sT[1][ni][r] = 0.f; }
      const int rowa = (ni >> 1) * 32 + (ni & 1) * 4 + frp;
      const int sz = swz4(rowa);
#pragma unroll
      for (int c = 0; c < 4; ++c) {
        bf16x8 kf = *(const bf16x8*)(KsC + rowa * 256 + ((c * 64 + quad * 16) ^ sz));
        sT[0][ni] = __builtin_amdgcn_mfma_f32_16x16x32_bf16(kf, qf0[c], sT[0][ni], 0, 0, 0);
        sT[1][ni] = __builtin_amdgcn_mfma_f32_16x16x32_bf16(kf, qf1[c], sT[1][ni], 0, 0, 0);
      }
    }
    __builtin_amdgcn_s_setprio(0);
    // online softmax in log2 domain, per q-frag
    union { u32 w[4]; bf16x8 v; } pa[2][4];
#pragma unroll
    for (int f = 0; f < 2; ++f) {
      float mt = sT[f][0][0];
#pragma unroll
      for (int ni = 0; ni < 8; ++ni)
#pragma unroll
        for (int r = 0; r < 4; ++r) mt = fmaxf(mt, sT[f][ni][r]);
      mt = fmaxf(mt, __shfl_xor(mt, 16));
      mt = fmaxf(mt, __shfl_xor(mt, 32));
      if (!__all(mt <= m_run[f] + 10.f)) {
        float mnew = fmaxf(m_run[f], mt);
        float alpha = exp2_fast(m_run[f] - mnew);
        m_run[f] = mnew;
        l_run[f] *= alpha;
#pragma unroll
        for (int i = 0; i < 8; ++i)
#pragma unroll
          for (int r = 0; r < 4; ++r) oT[f][i][r] *= alpha;
      }
      float lt = 0.f;
#pragma unroll
      for (int ni = 0; ni < 8; ++ni)
#pragma unroll
        for (int r = 0; r < 4; ++r) {
          sT[f][ni][r] = exp2_fast(sT[f][ni][r] - m_run[f]);
          lt += sT[f][ni][r];
        }
      lt += __shfl_xor(lt, 16);
      lt += __shfl_xor(lt, 32);
      l_run[f] += lt;
#pragma unroll
      for (int kk = 0; kk < 4; ++kk) {
        pa[f][kk].w[0] = cvtpk(sT[f][kk * 2][0], sT[f][kk * 2][1]);
        pa[f][kk].w[1] = cvtpk(sT[f][kk * 2][2], sT[f][kk * 2][3]);
        pa[f][kk].w[2] = cvtpk(sT[f][kk * 2 + 1][0], sT[f][kk * 2 + 1][1]);
        pa[f][kk].w[3] = cvtpk(sT[f][kk * 2 + 1][2], sT[f][kk * 2 + 1][3]);
      }
    }
    // O^T += V^T @ P for both q-frags, vf read ONCE per (ni2,kk)
    __builtin_amdgcn_s_setprio(1);
#pragma unroll
    for (int ni2 = 0; ni2 < 8; ++ni2) {
      const int rowv = ni2 * 16 + fr;
      const int sz = swz4(rowv);
#pragma unroll
      for (int kk = 0; kk < 4; ++kk) {
        bf16x8 vf = *(const bf16x8*)(VsC + rowv * 256 + ((kk * 64 + quad * 16) ^ sz));
        oT[0][ni2] = __builtin_amdgcn_mfma_f32_16x16x32_bf16(vf, pa[0][kk].v, oT[0][ni2], 0, 0, 0);
        oT[1][ni2] = __builtin_amdgcn_mfma_f32_16x16x32_bf16(vf, pa[1][kk].v, oT[1][ni2], 0, 0, 0);
      }
    }
    __builtin_amdgcn_s_setprio(0);
    __builtin_amdgcn_sched_barrier(0);
    __builtin_amdgcn_s_barrier();
    cur ^= 1;
  }
  // write unnormalized partials: Opart[half][(b*1024+q)*16+h][128 d]
#pragma unroll
  for (int f = 0; f < 2; ++f) {
    const size_t row = (size_t)(b * N2T + q0 + f * 16 + fr) * 16 + h;
    float* op = Opart + ((size_t)half * 32768 + row) * 128 + quad * 4;
#pragma unroll
    for (int ni2 = 0; ni2 < 8; ++ni2) {
      float4 v4 = {oT[f][ni2][0], oT[f][ni2][1], oT[f][ni2][2], oT[f][ni2][3]};
      *(float4*)(op + ni2 * 16) = v4;
    }
    if (quad == 0) {
      float2 v2 = {m_run[f], l_run[f]};
      *(float2*)(ml + ((size_t)half * 32768 + row) * 2) = v2;
    }
  }
}

// ------------- combine: merge 2 kv-half partials -> ab bf16 -------------
__global__ __launch_bounds__(256) void combine2_kernel(
    const float* __restrict__ Opart, const float* __restrict__ ml,
    u16* __restrict__ ab) {
  const int tid = blockIdx.x * 256 + threadIdx.x;  // 1,048,576 total
  const int row = tid >> 5;
  const int c = tid & 31;
  float2 ml1 = *(const float2*)(ml + (size_t)row * 2);
  float2 ml2 = *(const float2*)(ml + ((size_t)32768 + row) * 2);
  float m = fmaxf(ml1.x, ml2.x);
  float w1 = exp2_fast(ml1.x - m), w2 = exp2_fast(ml2.x - m);
  float inv = 1.0f / (w1 * ml1.y + w2 * ml2.y);
  float4 o1 = *(const float4*)(Opart + (size_t)row * 128 + c * 4);
  float4 o2 = *(const float4*)(Opart + ((size_t)32768 + row) * 128 + c * 4);
  union { ushort4 v4; u16 hh[4]; } pk;
  pk.hh[0] = f2bf((w1 * o1.x + w2 * o2.x) * inv);
  pk.hh[1] = f2bf((w1 * o1.y + w2 * o2.y) * inv);
  pk.hh[2] = f2bf((w1 * o1.z + w2 * o2.z) * inv);
  pk.hh[3] = f2bf((w1 * o1.w + w2 * o2.w) * inv);
  *(ushort4*)(ab + (size_t)(row >> 4) * 2048 + (row & 15) * 128 + c * 4) = pk.v4;
}

extern "C" void kernel_launch(void* const* d_in, const int* in_sizes, int n_in,
                              void* d_out, int out_size, void* d_ws, size_t ws_size,
                              hipStream_t stream) {
  const float* x = (const float*)d_in[0];
  const float* latents = (const float*)d_in[1];
  const float* ln1g = (const float*)d_in[2];
  const float* ln1b = (const float*)d_in[3];
  const float* ln2g = (const float*)d_in[4];
  const float* ln2b = (const float*)d_in[5];
  const float* Wq = (const float*)d_in[6];
  const float* Wkv = (const float*)d_in[7];
  const float* Wout = (const float*)d_in[8];

  char* w = (char*)d_ws;
  u16* xn = (u16*)w;   w += (size_t)8192 * 2048 * 2;   // 32.0 MB
  u16* lnb = (u16*)w;  w += (size_t)2048 * 3072 * 2;   // 12.6 MB
  u16* WqT = (u16*)w;  w += (size_t)2048 * 3072 * 2;
  u16* WkvT = (u16*)w; w += (size_t)4096 * 2048 * 2;
  u16* WoT = (u16*)w;  w += (size_t)3072 * 2048 * 2;
  u16* qb = (u16*)w;   w += (size_t)2048 * 2048 * 2;
  u16* kb = (u16*)w;   w += (size_t)8192 * 2048 * 2;
  u16* vtb = (u16*)w;  w += (size_t)2 * 2048 * 4096 * 2;
  u16* ab = (u16*)w;   w += (size_t)2048 * 2048 * 2;
  // attention partials OVERLAY xn+lnb (both dead before attn runs):
  // opart 2*32768*128*4B = 33.55 MB + ml 0.5 MB < 44.6 MB ✓
  float* opart = (float*)d_ws;
  float* mlbuf = (float*)((char*)d_ws + 33554432);

  dim3 blk(256);
  tcast_kernel<<<dim3(48, 32), blk, 0, stream>>>(Wq, WqT, 3072, 2048);
  tcast_kernel<<<dim3(32, 64), blk, 0, stream>>>(Wkv, WkvT, 2048, 4096);
  tcast_kernel<<<dim3(32, 48), blk, 0, stream>>>(Wout, WoT, 2048, 3072);
  ln_cast_kernel<2><<<8192, blk, 0, stream>>>(x, ln1g, ln1b, xn);
  ln_cast_kernel<3><<<2048, blk, 0, stream>>>(latents, ln2g, ln2b, lnb);

  const float scale = 0.29730177875068026f;            // 1/sqrt(sqrt(128))
  const float qscale = scale * 1.4426950408889634f;    // fold log2e into q
  gemm_bt_kernel<1><<<dim3(16, 16, 1), blk, 0, stream>>>(
      lnb, 0, WqT, 0, qb, 0, 2048, 2048, 3072, qscale);
  gemm256_dual_kernel<<<dim3(512), dim3(512), 0, stream>>>(
      xn, WkvT, kb, vtb, scale);
  attn_kernel<<<dim3(256), dim3(512), 0, stream>>>(qb, kb, vtb, opart, mlbuf);
  combine2_kernel<<<dim3(4096), blk, 0, stream>>>(opart, mlbuf, ab);
  gemm_bt_kernel<0><<<dim3(16, 24, 1), blk, 0, stream>>>(
      ab, 0, WoT, 0, d_out, 0, 2048, 3072, 2048, 1.0f);
}

// Round 16
// 371.799 us; speedup vs baseline: 1.0436x; 1.0365x over previous
//
#include <hip/hip_runtime.h>
#include <stdint.h>

typedef unsigned short u16;
typedef unsigned int u32;
typedef __attribute__((ext_vector_type(4))) float f32x4;
typedef __attribute__((ext_vector_type(8))) __bf16 bf16x8;

#define N1T 4096
#define N2T 1024
#define DIMT 3072
#define KVD 2048
#define INN 2048
#define NH 16
#define DH 128

__device__ __forceinline__ u16 f2bf(float f) {
  u32 u = __builtin_bit_cast(u32, f);
  u = (u + 0x7fffu + ((u >> 16) & 1u)) >> 16;
  return (u16)u;
}

__device__ __forceinline__ float exp2_fast(float x) {
  return __builtin_amdgcn_exp2f(x);  // v_exp_f32 (native 2^x)
}

__device__ __forceinline__ u32 cvtpk(float lo, float hi) {
  u32 r;
  asm volatile("v_cvt_pk_bf16_f32 %0, %1, %2" : "=v"(r) : "v"(lo), "v"(hi));
  return r;
}

typedef __attribute__((address_space(1))) void gvoid_t;
typedef __attribute__((address_space(3))) void lvoid_t;

__device__ __forceinline__ void gload16(const void* g, void* l) {
  __builtin_amdgcn_global_load_lds((gvoid_t*)g, (lvoid_t*)l, 16, 0, 0);
}

// ---------------- preprocessing bodies ----------------
template<int NV>  // NV float4 per thread; D = NV*1024
__device__ __forceinline__ void ln_body(
    const float* __restrict__ X, const float* __restrict__ G,
    const float* __restrict__ B, u16* __restrict__ out, int row_) {
  const int D = NV * 1024;
  const int t = threadIdx.x;
  const size_t row = row_;
  const float4* xr = (const float4*)(X + row * D);
  float4 v[NV];
  float s = 0.f, ss = 0.f;
#pragma unroll
  for (int i = 0; i < NV; ++i) {
    v[i] = xr[i * 256 + t];
    s += v[i].x + v[i].y + v[i].z + v[i].w;
    ss += v[i].x * v[i].x + v[i].y * v[i].y + v[i].z * v[i].z + v[i].w * v[i].w;
  }
#pragma unroll
  for (int off = 32; off; off >>= 1) {
    s += __shfl_xor(s, off);
    ss += __shfl_xor(ss, off);
  }
  __shared__ float red[2][4];
  const int wave = t >> 6, lane = t & 63;
  if (lane == 0) { red[0][wave] = s; red[1][wave] = ss; }
  __syncthreads();
  s = red[0][0] + red[0][1] + red[0][2] + red[0][3];
  ss = red[1][0] + red[1][1] + red[1][2] + red[1][3];
  const float mu = s / D;
  const float rstd = rsqrtf(ss / D - mu * mu + 1e-5f);
  u16* orow = out + row * D;
#pragma unroll
  for (int i = 0; i < NV; ++i) {
    const int idx = (i * 256 + t) * 4;
    float4 g4 = *(const float4*)(G + idx);
    float4 b4 = *(const float4*)(B + idx);
    union { ushort4 v4; u16 h[4]; } pk;
    pk.h[0] = f2bf((v[i].x - mu) * rstd * g4.x + b4.x);
    pk.h[1] = f2bf((v[i].y - mu) * rstd * g4.y + b4.y);
    pk.h[2] = f2bf((v[i].z - mu) * rstd * g4.z + b4.z);
    pk.h[3] = f2bf((v[i].w - mu) * rstd * g4.w + b4.w);
    *(ushort4*)(orow + idx) = pk.v4;
  }
}

__device__ __forceinline__ void tcast_body(
    const float* __restrict__ W, u16* __restrict__ WT, int K, int N,
    int bx, int by) {
  __shared__ __align__(16) u16 tile[64][72];
  const int t = threadIdx.x;
  const int k0 = bx * 64, n0 = by * 64;
#pragma unroll
  for (int i = 0; i < 4; ++i) {
    int idx = i * 256 + t;
    int r = idx >> 4, c = (idx & 15) << 2;
    float4 v = *(const float4*)(W + (size_t)(k0 + r) * N + n0 + c);
    union { ushort4 v4; u16 h[4]; } pk;
    pk.h[0] = f2bf(v.x); pk.h[1] = f2bf(v.y);
    pk.h[2] = f2bf(v.z); pk.h[3] = f2bf(v.w);
    *(ushort4*)&tile[r][c] = pk.v4;
  }
  __syncthreads();
#pragma unroll
  for (int j = 0; j < 2; ++j) {
    int cid = j * 256 + t;
    int nr = cid >> 3, kc = (cid & 7) << 3;
    union { uint4 v4; u16 h[8]; } pk;
#pragma unroll
    for (int jj = 0; jj < 8; ++jj) pk.h[jj] = tile[kc + jj][nr];
    *(uint4*)(WT + (size_t)(n0 + nr) * K + k0 + kc) = pk.v4;
  }
}

// one launch for all 5 preprocessing jobs (block-range dispatch):
// [0,8192) LN(x); [8192,10240) LN(latents); then the 3 weight tcasts.
// All BW-bound; merging removes 4 launch gaps and overlaps the streams.
__global__ __launch_bounds__(256) void preproc_kernel(
    const float* __restrict__ x, const float* __restrict__ ln1g,
    const float* __restrict__ ln1b, u16* __restrict__ xn,
    const float* __restrict__ latents, const float* __restrict__ ln2g,
    const float* __restrict__ ln2b, u16* __restrict__ lnb,
    const float* __restrict__ Wq, u16* __restrict__ WqT,
    const float* __restrict__ Wkv, u16* __restrict__ WkvT,
    const float* __restrict__ Wout, u16* __restrict__ WoT) {
  int r = blockIdx.x;
  if (r < 8192) { ln_body<2>(x, ln1g, ln1b, xn, r); return; }
  r -= 8192;
  if (r < 2048) { ln_body<3>(latents, ln2g, ln2b, lnb, r); return; }
  r -= 2048;
  if (r < 1536) { tcast_body(Wq, WqT, 3072, 2048, r % 48, r / 48); return; }
  r -= 1536;
  if (r < 2048) { tcast_body(Wkv, WkvT, 2048, 4096, r % 32, r / 32); return; }
  r -= 2048;
  tcast_body(Wout, WoT, 2048, 3072, r % 32, r / 32);
}

// ------------- GEMM 128x128 (m97-structure) -------------
template<int BF16OUT>
__global__ __launch_bounds__(256) void gemm_bt_kernel(
    const u16* __restrict__ A, size_t Az,
    const u16* __restrict__ Bt, size_t Btz,
    void* __restrict__ Cv, size_t Cz,
    int M, int N, int K, float scale) {
  __shared__ __align__(16) u16 As[128 * 64];
  __shared__ __align__(16) u16 Bs[128 * 64];
  A += (size_t)blockIdx.z * Az;
  Bt += (size_t)blockIdx.z * Btz;
  const int t = threadIdx.x, lane = t & 63, wave = t >> 6;
  const int m0 = blockIdx.x * 128, n0 = blockIdx.y * 128;
  const int wr = (wave >> 1) * 64, wc = (wave & 1) * 64;
  const int fr = lane & 15, fk = (lane >> 4) * 8;
  f32x4 acc[4][4];
#pragma unroll
  for (int i = 0; i < 4; ++i)
#pragma unroll
    for (int j = 0; j < 4; ++j)
#pragma unroll
      for (int r = 0; r < 4; ++r) acc[i][j][r] = 0.f;
  const int srow = t >> 3;
  const int scb = (t & 7) * 16;
  const int nk = K >> 6;
  for (int kt = 0; kt < nk; ++kt) {
    const char* Ab = (const char*)(A + (size_t)kt * 64);
    const char* Bb = (const char*)(Bt + (size_t)kt * 64);
#pragma unroll
    for (int r = 0; r < 4; ++r) {
      int row = srow + r * 32;
      gload16(Ab + (size_t)(m0 + row) * K * 2 + scb, (char*)As + t * 16 + r * 4096);
      gload16(Bb + (size_t)(n0 + row) * K * 2 + scb, (char*)Bs + t * 16 + r * 4096);
    }
    __syncthreads();
#pragma unroll
    for (int kk = 0; kk < 2; ++kk) {
      bf16x8 af[4], bfr[4];
#pragma unroll
      for (int i = 0; i < 4; ++i)
        af[i] = *(const bf16x8*)&As[(wr + i * 16 + fr) * 64 + kk * 32 + fk];
#pragma unroll
      for (int j = 0; j < 4; ++j)
        bfr[j] = *(const bf16x8*)&Bs[(wc + j * 16 + fr) * 64 + kk * 32 + fk];
#pragma unroll
      for (int i = 0; i < 4; ++i)
#pragma unroll
        for (int j = 0; j < 4; ++j)
          acc[i][j] = __builtin_amdgcn_mfma_f32_16x16x32_bf16(af[i], bfr[j], acc[i][j], 0, 0, 0);
    }
    __syncthreads();
  }
  const int cr = (lane >> 4) * 4, cc = lane & 15;
#pragma unroll
  for (int i = 0; i < 4; ++i)
#pragma unroll
    for (int j = 0; j < 4; ++j) {
      const int row = m0 + wr + i * 16 + cr;
      const int col = n0 + wc + j * 16 + cc;
      if (BF16OUT) {
        u16* C = (u16*)Cv + (size_t)blockIdx.z * Cz;
#pragma unroll
        for (int r = 0; r < 4; ++r) C[(size_t)(row + r) * N + col] = f2bf(acc[i][j][r] * scale);
      } else {
        float* C = (float*)Cv + (size_t)blockIdx.z * Cz;
#pragma unroll
        for (int r = 0; r < 4; ++r) C[(size_t)(row + r) * N + col] = acc[i][j][r];
      }
    }
}

// ------------- GEMM 256x256 body (single-buffered R7 schedule) -------------
__device__ __forceinline__ void stage_region(const u16* __restrict__ G, int ldk,
                                             int rowbase, int colbase,
                                             u16* lds, int t) {
  const int srow = t >> 2, sc = t & 3;
  const int swz = (srow >> 1) & 3;
#pragma unroll
  for (int r = 0; r < 2; ++r) {
    int row = r * 128 + srow;
    gload16(G + (size_t)(rowbase + row) * ldk + colbase + (sc ^ swz) * 8,
            (char*)lds + t * 16 + r * 8192);
  }
}

#define GPHASE(MSUB, KK, STAGE_STMT, RELOAD_B, VM0)                               \
  {                                                                               \
    STAGE_STMT;                                                                   \
    const u16* Aarr = (KK) ? A1s : A0s;                                           \
    _Pragma("unroll")                                                             \
    for (int fi = 0; fi < 4; ++fi) {                                              \
      int rowa = RM + (MSUB) * 64 + fi * 16 + fr;                                 \
      af[fi] = *(const bf16x8*)((const char*)Aarr + rowa * 64 +                   \
                                ((q ^ ((rowa >> 1) & 3)) * 16));                  \
    }                                                                             \
    if (RELOAD_B) {                                                               \
      const u16* Barr = (KK) ? B1s : B0s;                                         \
      _Pragma("unroll")                                                           \
      for (int j = 0; j < 4; ++j) {                                               \
        int rowb = RN + j * 16 + fr;                                              \
        bf[j] = *(const bf16x8*)((const char*)Barr + rowb * 64 +                  \
                                 ((q ^ ((rowb >> 1) & 3)) * 16));                 \
      }                                                                           \
    }                                                                             \
    if (VM0) { asm volatile("s_waitcnt vmcnt(0)" ::: "memory"); }                 \
    else     { asm volatile("s_waitcnt vmcnt(2)" ::: "memory"); }                 \
    __builtin_amdgcn_s_barrier();                                                 \
    asm volatile("s_waitcnt lgkmcnt(0)" ::: "memory");                            \
    __builtin_amdgcn_sched_barrier(0);                                            \
    __builtin_amdgcn_s_setprio(1);                                                \
    _Pragma("unroll")                                                             \
    for (int fi = 0; fi < 4; ++fi)                                                \
      _Pragma("unroll")                                                           \
      for (int j = 0; j < 4; ++j)                                                 \
        acc[(MSUB) * 4 + fi][j] = __builtin_amdgcn_mfma_f32_16x16x32_bf16(        \
            af[fi], bf[j], acc[(MSUB) * 4 + fi][j], 0, 0, 0);                     \
    __builtin_amdgcn_s_setprio(0);                                                \
    __builtin_amdgcn_s_barrier();                                                 \
  }

__device__ __forceinline__ void gemm256_body(
    const u16* __restrict__ A, const u16* __restrict__ Bt, u16* __restrict__ C,
    int N, int K, float scale, int bx, int by,
    u16* A0s, u16* A1s, u16* B0s, u16* B1s, int t) {
  const int lane = t & 63, wave = t >> 6;
  const int m0 = bx * 256, n0 = by * 256;
  const int RM = (wave >> 2) * 128, RN = (wave & 3) * 64;
  const int fr = lane & 15, q = lane >> 4;
  f32x4 acc[8][4];
#pragma unroll
  for (int i = 0; i < 8; ++i)
#pragma unroll
    for (int j = 0; j < 4; ++j)
#pragma unroll
      for (int r = 0; r < 4; ++r) acc[i][j][r] = 0.f;

  stage_region(Bt, K, n0, 0, B0s, t);
  stage_region(A, K, m0, 0, A0s, t);
  stage_region(Bt, K, n0, 32, B1s, t);
  asm volatile("s_waitcnt vmcnt(0)" ::: "memory");
  __builtin_amdgcn_s_barrier();

  const int nk = K >> 6;
#pragma unroll 1
  for (int kt = 0; kt < nk; ++kt) {
    const bool last = (kt == nk - 1);
    bf16x8 af[4], bf[4];
    GPHASE(0, 0, stage_region(A, K, m0, kt * 64 + 32, A1s, t), true, false)
    GPHASE(1, 0, if (!last) stage_region(Bt, K, n0, (kt + 1) * 64, B0s, t), false, last)
    GPHASE(1, 1, if (!last) stage_region(A, K, m0, (kt + 1) * 64, A0s, t), true, last)
    GPHASE(0, 1, if (!last) stage_region(Bt, K, n0, (kt + 1) * 64 + 32, B1s, t), false, last)
  }

  const int cr = (lane >> 4) * 4, cc = lane & 15;
#pragma unroll
  for (int i = 0; i < 8; ++i)
#pragma unroll
    for (int j = 0; j < 4; ++j) {
      const int row = m0 + RM + i * 16 + cr;
      const int col = n0 + RN + j * 16 + cc;
#pragma unroll
      for (int r = 0; r < 4; ++r) C[(size_t)(row + r) * N + col] = f2bf(acc[i][j][r] * scale);
    }
}

// merged k-GEMM + vt-GEMM with XCD-aware block placement (T1; FETCH 184->98MB).
__global__ __launch_bounds__(512) void gemm256_dual_kernel(
    const u16* __restrict__ xn, const u16* __restrict__ WkvT,
    u16* __restrict__ kb, u16* __restrict__ vtb, float kscale) {
  __shared__ __align__(16) u16 A0s[256 * 32];
  __shared__ __align__(16) u16 A1s[256 * 32];
  __shared__ __align__(16) u16 B0s[256 * 32];
  __shared__ __align__(16) u16 B1s[256 * 32];
  const int t = threadIdx.x;
  const int bid = blockIdx.x;
  const int l = (bid & 7) * 64 + (bid >> 3);  // bijective XCD-chunk remap
  if (l < 256) {
    const int g = l >> 6, r = l & 63;
    gemm256_body(xn, WkvT, kb, 2048, 2048, kscale,
                 g * 8 + (r & 7), r >> 3, A0s, A1s, B0s, B1s, t);
  } else {
    const int l2 = l - 256;
    const int g = l2 >> 6, r = l2 & 63;
    const int z = g >> 1;
    gemm256_body(WkvT + (size_t)2048 * 2048, xn + (size_t)z * 4096 * 2048,
                 vtb + (size_t)z * 2048 * 4096, 4096, 2048, 1.0f,
                 r & 7, (g & 1) * 8 + (r >> 3), A0s, A1s, B0s, B1s, t);
  }
}

// ------------- flash attention v4 (proven 86us): 32 q/wave, KV-split-2 -------------
#define KVB 128
__device__ __forceinline__ int swz4(int row) {
  return ((row & 15) ^ (((row >> 4) & 1) << 2)) << 4;
}

__device__ __forceinline__ void stage_kv(const u16* Kbase, const u16* Vbase,
                                         int kv0, char* ks, char* vs, int t) {
  const int col = (t & 15) * 16;
#pragma unroll
  for (int r = 0; r < 4; ++r) {
    int row = (t >> 4) + r * 32;
    gload16((const char*)(Kbase + (size_t)(kv0 + row) * INN) + (col ^ swz4(row)),
            ks + t * 16 + r * 8192);
  }
#pragma unroll
  for (int r = 0; r < 4; ++r) {
    int row = (t >> 4) + r * 32;
    gload16((const char*)(Vbase + (size_t)row * N1T + kv0) + (col ^ swz4(row)),
            vs + t * 16 + r * 8192);
  }
}

__global__ __launch_bounds__(512, 2) void attn_kernel(
    const u16* __restrict__ Q, const u16* __restrict__ Kb,
    const u16* __restrict__ Vt, float* __restrict__ Opart,
    float* __restrict__ ml) {
  __shared__ __align__(16) u16 Ks[2][KVB * 128];   // [key][d]
  __shared__ __align__(16) u16 Vs[2][128 * KVB];   // [d][key]
  const int t = threadIdx.x, lane = t & 63, wave = t >> 6;
  const int bid = blockIdx.x;
  const int xcd = bid & 7, idx = bid >> 3;
  const int bh = (xcd << 2) | (idx >> 3);
  const int sub = idx & 7;
  const int qt = sub >> 1, half = sub & 1;
  const int b = bh >> 4, h = bh & 15;
  const int q0 = qt * 256 + wave * 32;
  const int fr = lane & 15, quad = lane >> 4;
  const int fk = quad * 8;
  const int frp = fr + (fr & 12);  // perm row offset

  bf16x8 qf0[4], qf1[4];
  {
    const u16* qr0 = Q + (size_t)(b * N2T + q0 + fr) * INN + h * DH;
    const u16* qr1 = Q + (size_t)(b * N2T + q0 + 16 + fr) * INN + h * DH;
#pragma unroll
    for (int c = 0; c < 4; ++c) {
      qf0[c] = *(const bf16x8*)(qr0 + c * 32 + fk);
      qf1[c] = *(const bf16x8*)(qr1 + c * 32 + fk);
    }
  }

  float m_run[2] = {-1e30f, -1e30f}, l_run[2] = {0.f, 0.f};
  f32x4 oT[2][8];
#pragma unroll
  for (int f = 0; f < 2; ++f)
#pragma unroll
    for (int i = 0; i < 8; ++i)
#pragma unroll
      for (int r = 0; r < 4; ++r) oT[f][i][r] = 0.f;

  const u16* Kbase = Kb + (size_t)(b * N1T) * INN + h * DH;
  const u16* Vbase = Vt + ((size_t)b * INN + h * DH) * N1T;
  const int kvb = half * 2048;

  const int NT = 2048 / KVB;  // 16 tiles
  int cur = 0;
  stage_kv(Kbase, Vbase, kvb, (char*)&Ks[0][0], (char*)&Vs[0][0], t);
  for (int tile = 0; tile < NT; ++tile) {
    if (tile + 1 < NT) {
      stage_kv(Kbase, Vbase, kvb + (tile + 1) * KVB, (char*)&Ks[cur ^ 1][0],
               (char*)&Vs[cur ^ 1][0], t);
      asm volatile("s_waitcnt vmcnt(8)" ::: "memory");
    } else {
      asm volatile("s_waitcnt vmcnt(0)" ::: "memory");
    }
    __builtin_amdgcn_s_barrier();
    __builtin_amdgcn_sched_barrier(0);
    const char* KsC = (const char*)&Ks[cur][0];
    const char* VsC = (const char*)&Vs[cur][0];

    // S^T = K_perm @ Q^T for both q-frags, kf read ONCE per (ni,c)
    f32x4 sT[2][8];
    __builtin_amdgcn_s_setprio(1);
#pragma unroll
    for (int ni = 0; ni < 8; ++ni) {
#pragma unroll
      for (int r = 0; r < 4; ++r) { sT[0][ni][r] = 0.f; sT[1][ni][r] = 0.f; }
      const int rowa = (ni >> 1) * 32 + (ni & 1) * 4 + frp;
      const int sz = swz4(rowa);
#pragma unroll
      for (int c = 0; c < 4; ++c) {
        bf16x8 kf = *(const bf16x8*)(KsC + rowa * 256 + ((c * 64 + quad * 16) ^ sz));
        sT[0][ni] = __builtin_amdgcn_mfma_f32_16x16x32_bf16(kf, qf0[c], sT[0][ni], 0, 0, 0);
        sT[1][ni] = __builtin_amdgcn_mfma_f32_16x16x32_bf16(kf, qf1[c], sT[1][ni], 0, 0, 0);
      }
    }
    __builtin_amdgcn_s_setprio(0);
    // online softmax in log2 domain, per q-frag
    union { u32 w[4]; bf16x8 v; } pa[2][4];
#pragma unroll
    for (int f = 0; f < 2; ++f) {
      float mt = sT[f][0][0];
#pragma unroll
      for (int ni = 0; ni < 8; ++ni)
#pragma unroll
        for (int r = 0; r < 4; ++r) mt = fmaxf(mt, sT[f][ni][r]);
      mt = fmaxf(mt, __shfl_xor(mt, 16));
      mt = fmaxf(mt, __shfl_xor(mt, 32));
      if (!__all(mt <= m_run[f] + 10.f)) {
        float mnew = fmaxf(m_run[f], mt);
        float alpha = exp2_fast(m_run[f] - mnew);
        m_run[f] = mnew;
        l_run[f] *= alpha;
#pragma unroll
        for (int i = 0; i < 8; ++i)
#pragma unroll
          for (int r = 0; r < 4; ++r) oT[f][i][r] *= alpha;
      }
      float lt = 0.f;
#pragma unroll
      for (int ni = 0; ni < 8; ++ni)
#pragma unroll
        for (int r = 0; r < 4; ++r) {
          sT[f][ni][r] = exp2_fast(sT[f][ni][r] - m_run[f]);
          lt += sT[f][ni][r];
        }
      lt += __shfl_xor(lt, 16);
      lt += __shfl_xor(lt, 32);
      l_run[f] += lt;
#pragma unroll
      for (int kk = 0; kk < 4; ++kk) {
        pa[f][kk].w[0] = cvtpk(sT[f][kk * 2][0], sT[f][kk * 2][1]);
        pa[f][kk].w[1] = cvtpk(sT[f][kk * 2][2], sT[f][kk * 2][3]);
        pa[f][kk].w[2] = cvtpk(sT[f][kk * 2 + 1][0], sT[f][kk * 2 + 1][1]);
        pa[f][kk].w[3] = cvtpk(sT[f][kk * 2 + 1][2], sT[f][kk * 2 + 1][3]);
      }
    }
    // O^T += V^T @ P for both q-frags, vf read ONCE per (ni2,kk)
    __builtin_amdgcn_s_setprio(1);
#pragma unroll
    for (int ni2 = 0; ni2 < 8; ++ni2) {
      const int rowv = ni2 * 16 + fr;
      const int sz = swz4(rowv);
#pragma unroll
      for (int kk = 0; kk < 4; ++kk) {
        bf16x8 vf = *(const bf16x8*)(VsC + rowv * 256 + ((kk * 64 + quad * 16) ^ sz));
        oT[0][ni2] = __builtin_amdgcn_mfma_f32_16x16x32_bf16(vf, pa[0][kk].v, oT[0][ni2], 0, 0, 0);
        oT[1][ni2] = __builtin_amdgcn_mfma_f32_16x16x32_bf16(vf, pa[1][kk].v, oT[1][ni2], 0, 0, 0);
      }
    }
    __builtin_amdgcn_s_setprio(0);
    __builtin_amdgcn_sched_barrier(0);
    __builtin_amdgcn_s_barrier();
    cur ^= 1;
  }
  // write unnormalized partials: Opart[half][(b*1024+q)*16+h][128 d]
#pragma unroll
  for (int f = 0; f < 2; ++f) {
    const size_t row = (size_t)(b * N2T + q0 + f * 16 + fr) * 16 + h;
    float* op = Opart + ((size_t)half * 32768 + row) * 128 + quad * 4;
#pragma unroll
    for (int ni2 = 0; ni2 < 8; ++ni2) {
      float4 v4 = {oT[f][ni2][0], oT[f][ni2][1], oT[f][ni2][2], oT[f][ni2][3]};
      *(float4*)(op + ni2 * 16) = v4;
    }
    if (quad == 0) {
      float2 v2 = {m_run[f], l_run[f]};
      *(float2*)(ml + ((size_t)half * 32768 + row) * 2) = v2;
    }
  }
}

// ------------- combine: merge 2 kv-half partials -> ab bf16 -------------
__global__ __launch_bounds__(256) void combine2_kernel(
    const float* __restrict__ Opart, const float* __restrict__ ml,
    u16* __restrict__ ab) {
  const int tid = blockIdx.x * 256 + threadIdx.x;  // 1,048,576 total
  const int row = tid >> 5;
  const int c = tid & 31;
  float2 ml1 = *(const float2*)(ml + (size_t)row * 2);
  float2 ml2 = *(const float2*)(ml + ((size_t)32768 + row) * 2);
  float m = fmaxf(ml1.x, ml2.x);
  float w1 = exp2_fast(ml1.x - m), w2 = exp2_fast(ml2.x - m);
  float inv = 1.0f / (w1 * ml1.y + w2 * ml2.y);
  float4 o1 = *(const float4*)(Opart + (size_t)row * 128 + c * 4);
  float4 o2 = *(const float4*)(Opart + ((size_t)32768 + row) * 128 + c * 4);
  union { ushort4 v4; u16 hh[4]; } pk;
  pk.hh[0] = f2bf((w1 * o1.x + w2 * o2.x) * inv);
  pk.hh[1] = f2bf((w1 * o1.y + w2 * o2.y) * inv);
  pk.hh[2] = f2bf((w1 * o1.z + w2 * o2.z) * inv);
  pk.hh[3] = f2bf((w1 * o1.w + w2 * o2.w) * inv);
  *(ushort4*)(ab + (size_t)(row >> 4) * 2048 + (row & 15) * 128 + c * 4) = pk.v4;
}

extern "C" void kernel_launch(void* const* d_in, const int* in_sizes, int n_in,
                              void* d_out, int out_size, void* d_ws, size_t ws_size,
                              hipStream_t stream) {
  const float* x = (const float*)d_in[0];
  const float* latents = (const float*)d_in[1];
  const float* ln1g = (const float*)d_in[2];
  const float* ln1b = (const float*)d_in[3];
  const float* ln2g = (const float*)d_in[4];
  const float* ln2b = (const float*)d_in[5];
  const float* Wq = (const float*)d_in[6];
  const float* Wkv = (const float*)d_in[7];
  const float* Wout = (const float*)d_in[8];

  char* w = (char*)d_ws;
  u16* xn = (u16*)w;   w += (size_t)8192 * 2048 * 2;   // 32.0 MB
  u16* lnb = (u16*)w;  w += (size_t)2048 * 3072 * 2;   // 12.6 MB
  u16* WqT = (u16*)w;  w += (size_t)2048 * 3072 * 2;
  u16* WkvT = (u16*)w; w += (size_t)4096 * 2048 * 2;
  u16* WoT = (u16*)w;  w += (size_t)3072 * 2048 * 2;
  u16* qb = (u16*)w;   w += (size_t)2048 * 2048 * 2;
  u16* kb = (u16*)w;   w += (size_t)8192 * 2048 * 2;
  u16* vtb = (u16*)w;  w += (size_t)2 * 2048 * 4096 * 2;
  u16* ab = (u16*)w;   w += (size_t)2048 * 2048 * 2;
  // attention partials OVERLAY xn+lnb (both dead before attn runs):
  // opart 2*32768*128*4B = 33.55 MB + ml 0.5 MB < 44.6 MB ✓
  float* opart = (float*)d_ws;
  float* mlbuf = (float*)((char*)d_ws + 33554432);

  dim3 blk(256);
  // all 5 preprocessing jobs in ONE launch (15360 blocks; LN-x first)
  preproc_kernel<<<dim3(15360), blk, 0, stream>>>(
      x, ln1g, ln1b, xn, latents, ln2g, ln2b, lnb,
      Wq, WqT, Wkv, WkvT, Wout, WoT);

  const float scale = 0.29730177875068026f;            // 1/sqrt(sqrt(128))
  const float qscale = scale * 1.4426950408889634f;    // fold log2e into q
  gemm_bt_kernel<1><<<dim3(16, 16, 1), blk, 0, stream>>>(
      lnb, 0, WqT, 0, qb, 0, 2048, 2048, 3072, qscale);
  gemm256_dual_kernel<<<dim3(512), dim3(512), 0, stream>>>(
      xn, WkvT, kb, vtb, scale);
  attn_kernel<<<dim3(256), dim3(512), 0, stream>>>(qb, kb, vtb, opart, mlbuf);
  combine2_kernel<<<dim3(4096), blk, 0, stream>>>(opart, mlbuf, ab);
  gemm_bt_kernel<0><<<dim3(16, 24, 1), blk, 0, stream>>>(
      ab, 0, WoT, 0, d_out, 0, 2048, 3072, 2048, 1.0f);
}

// Round 17
// 366.709 us; speedup vs baseline: 1.0581x; 1.0139x over previous
//
#include <hip/hip_runtime.h>
#include <stdint.h>

typedef unsigned short u16;
typedef unsigned int u32;
typedef __attribute__((ext_vector_type(4))) float f32x4;
typedef __attribute__((ext_vector_type(8))) __bf16 bf16x8;

#define N1T 4096
#define N2T 1024
#define DIMT 3072
#define KVD 2048
#define INN 2048
#define NH 16
#define DH 128

__device__ __forceinline__ u16 f2bf(float f) {
  u32 u = __builtin_bit_cast(u32, f);
  u = (u + 0x7fffu + ((u >> 16) & 1u)) >> 16;
  return (u16)u;
}

__device__ __forceinline__ float exp2_fast(float x) {
  return __builtin_amdgcn_exp2f(x);  // v_exp_f32 (native 2^x)
}

__device__ __forceinline__ u32 cvtpk(float lo, float hi) {
  u32 r;
  asm volatile("v_cvt_pk_bf16_f32 %0, %1, %2" : "=v"(r) : "v"(lo), "v"(hi));
  return r;
}

typedef __attribute__((address_space(1))) void gvoid_t;
typedef __attribute__((address_space(3))) void lvoid_t;

__device__ __forceinline__ void gload16(const void* g, void* l) {
  __builtin_amdgcn_global_load_lds((gvoid_t*)g, (lvoid_t*)l, 16, 0, 0);
}

// ---------------- preprocessing bodies ----------------
template<int NV>  // NV float4 per thread; D = NV*1024
__device__ __forceinline__ void ln_body(
    const float* __restrict__ X, const float* __restrict__ G,
    const float* __restrict__ B, u16* __restrict__ out, int row_) {
  const int D = NV * 1024;
  const int t = threadIdx.x;
  const size_t row = row_;
  const float4* xr = (const float4*)(X + row * D);
  float4 v[NV];
  float s = 0.f, ss = 0.f;
#pragma unroll
  for (int i = 0; i < NV; ++i) {
    v[i] = xr[i * 256 + t];
    s += v[i].x + v[i].y + v[i].z + v[i].w;
    ss += v[i].x * v[i].x + v[i].y * v[i].y + v[i].z * v[i].z + v[i].w * v[i].w;
  }
#pragma unroll
  for (int off = 32; off; off >>= 1) {
    s += __shfl_xor(s, off);
    ss += __shfl_xor(ss, off);
  }
  __shared__ float red[2][4];
  const int wave = t >> 6, lane = t & 63;
  if (lane == 0) { red[0][wave] = s; red[1][wave] = ss; }
  __syncthreads();
  s = red[0][0] + red[0][1] + red[0][2] + red[0][3];
  ss = red[1][0] + red[1][1] + red[1][2] + red[1][3];
  const float mu = s / D;
  const float rstd = rsqrtf(ss / D - mu * mu + 1e-5f);
  u16* orow = out + row * D;
#pragma unroll
  for (int i = 0; i < NV; ++i) {
    const int idx = (i * 256 + t) * 4;
    float4 g4 = *(const float4*)(G + idx);
    float4 b4 = *(const float4*)(B + idx);
    union { ushort4 v4; u16 h[4]; } pk;
    pk.h[0] = f2bf((v[i].x - mu) * rstd * g4.x + b4.x);
    pk.h[1] = f2bf((v[i].y - mu) * rstd * g4.y + b4.y);
    pk.h[2] = f2bf((v[i].z - mu) * rstd * g4.z + b4.z);
    pk.h[3] = f2bf((v[i].w - mu) * rstd * g4.w + b4.w);
    *(ushort4*)(orow + idx) = pk.v4;
  }
}

__device__ __forceinline__ void tcast_body(
    const float* __restrict__ W, u16* __restrict__ WT, int K, int N,
    int bx, int by) {
  __shared__ __align__(16) u16 tile[64][72];
  const int t = threadIdx.x;
  const int k0 = bx * 64, n0 = by * 64;
#pragma unroll
  for (int i = 0; i < 4; ++i) {
    int idx = i * 256 + t;
    int r = idx >> 4, c = (idx & 15) << 2;
    float4 v = *(const float4*)(W + (size_t)(k0 + r) * N + n0 + c);
    union { ushort4 v4; u16 h[4]; } pk;
    pk.h[0] = f2bf(v.x); pk.h[1] = f2bf(v.y);
    pk.h[2] = f2bf(v.z); pk.h[3] = f2bf(v.w);
    *(ushort4*)&tile[r][c] = pk.v4;
  }
  __syncthreads();
#pragma unroll
  for (int j = 0; j < 2; ++j) {
    int cid = j * 256 + t;
    int nr = cid >> 3, kc = (cid & 7) << 3;
    union { uint4 v4; u16 h[8]; } pk;
#pragma unroll
    for (int jj = 0; jj < 8; ++jj) pk.h[jj] = tile[kc + jj][nr];
    *(uint4*)(WT + (size_t)(n0 + nr) * K + k0 + kc) = pk.v4;
  }
}

// one launch for all 5 preprocessing jobs (block-range dispatch)
__global__ __launch_bounds__(256) void preproc_kernel(
    const float* __restrict__ x, const float* __restrict__ ln1g,
    const float* __restrict__ ln1b, u16* __restrict__ xn,
    const float* __restrict__ latents, const float* __restrict__ ln2g,
    const float* __restrict__ ln2b, u16* __restrict__ lnb,
    const float* __restrict__ Wq, u16* __restrict__ WqT,
    const float* __restrict__ Wkv, u16* __restrict__ WkvT,
    const float* __restrict__ Wout, u16* __restrict__ WoT) {
  int r = blockIdx.x;
  if (r < 8192) { ln_body<2>(x, ln1g, ln1b, xn, r); return; }
  r -= 8192;
  if (r < 2048) { ln_body<3>(latents, ln2g, ln2b, lnb, r); return; }
  r -= 2048;
  if (r < 1536) { tcast_body(Wq, WqT, 3072, 2048, r % 48, r / 48); return; }
  r -= 1536;
  if (r < 2048) { tcast_body(Wkv, WkvT, 2048, 4096, r % 32, r / 32); return; }
  r -= 2048;
  tcast_body(Wout, WoT, 2048, 3072, r % 32, r / 32);
}

// ------------- GEMM 128x128 (m97-structure), bf16 out -------------
__global__ __launch_bounds__(256) void gemm_bt_kernel(
    const u16* __restrict__ A, const u16* __restrict__ Bt,
    u16* __restrict__ C, int M, int N, int K, float scale) {
  __shared__ __align__(16) u16 As[128 * 64];
  __shared__ __align__(16) u16 Bs[128 * 64];
  const int t = threadIdx.x, lane = t & 63, wave = t >> 6;
  const int m0 = blockIdx.x * 128, n0 = blockIdx.y * 128;
  const int wr = (wave >> 1) * 64, wc = (wave & 1) * 64;
  const int fr = lane & 15, fk = (lane >> 4) * 8;
  f32x4 acc[4][4];
#pragma unroll
  for (int i = 0; i < 4; ++i)
#pragma unroll
    for (int j = 0; j < 4; ++j)
#pragma unroll
      for (int r = 0; r < 4; ++r) acc[i][j][r] = 0.f;
  const int srow = t >> 3;
  const int scb = (t & 7) * 16;
  const int nk = K >> 6;
  for (int kt = 0; kt < nk; ++kt) {
    const char* Ab = (const char*)(A + (size_t)kt * 64);
    const char* Bb = (const char*)(Bt + (size_t)kt * 64);
#pragma unroll
    for (int r = 0; r < 4; ++r) {
      int row = srow + r * 32;
      gload16(Ab + (size_t)(m0 + row) * K * 2 + scb, (char*)As + t * 16 + r * 4096);
      gload16(Bb + (size_t)(n0 + row) * K * 2 + scb, (char*)Bs + t * 16 + r * 4096);
    }
    __syncthreads();
#pragma unroll
    for (int kk = 0; kk < 2; ++kk) {
      bf16x8 af[4], bfr[4];
#pragma unroll
      for (int i = 0; i < 4; ++i)
        af[i] = *(const bf16x8*)&As[(wr + i * 16 + fr) * 64 + kk * 32 + fk];
#pragma unroll
      for (int j = 0; j < 4; ++j)
        bfr[j] = *(const bf16x8*)&Bs[(wc + j * 16 + fr) * 64 + kk * 32 + fk];
#pragma unroll
      for (int i = 0; i < 4; ++i)
#pragma unroll
        for (int j = 0; j < 4; ++j)
          acc[i][j] = __builtin_amdgcn_mfma_f32_16x16x32_bf16(af[i], bfr[j], acc[i][j], 0, 0, 0);
    }
    __syncthreads();
  }
  const int cr = (lane >> 4) * 4, cc = lane & 15;
#pragma unroll
  for (int i = 0; i < 4; ++i)
#pragma unroll
    for (int j = 0; j < 4; ++j) {
      const int row = m0 + wr + i * 16 + cr;
      const int col = n0 + wc + j * 16 + cc;
#pragma unroll
      for (int r = 0; r < 4; ++r) C[(size_t)(row + r) * N + col] = f2bf(acc[i][j][r] * scale);
    }
}

// ------------- GEMM 128x96 tile, fp32 out (final GEMM, 2 blocks/CU balanced) ----
// N=3072 / 96 = 32 by-tiles; grid 16x32 = 512 blocks = exactly 2/CU (vs 384 =
// 1.5/CU at BN=128, which left half the machine idle in the tail). Wave layout
// 2x2, each wave 64x48 (acc[4][3]); Bs = [96][64] = 12KB, staged in 3 rounds.
__global__ __launch_bounds__(256) void gemm_bt96_kernel(
    const u16* __restrict__ A, const u16* __restrict__ Bt,
    float* __restrict__ C, int M, int N, int K) {
  __shared__ __align__(16) u16 As[128 * 64];
  __shared__ __align__(16) u16 Bs[96 * 64];
  const int t = threadIdx.x, lane = t & 63, wave = t >> 6;
  const int m0 = blockIdx.x * 128, n0 = blockIdx.y * 96;
  const int wr = (wave >> 1) * 64, wc = (wave & 1) * 48;
  const int fr = lane & 15, fk = (lane >> 4) * 8;
  f32x4 acc[4][3];
#pragma unroll
  for (int i = 0; i < 4; ++i)
#pragma unroll
    for (int j = 0; j < 3; ++j)
#pragma unroll
      for (int r = 0; r < 4; ++r) acc[i][j][r] = 0.f;
  const int srow = t >> 3;
  const int scb = (t & 7) * 16;
  const int nk = K >> 6;
  for (int kt = 0; kt < nk; ++kt) {
    const char* Ab = (const char*)(A + (size_t)kt * 64);
    const char* Bb = (const char*)(Bt + (size_t)kt * 64);
#pragma unroll
    for (int r = 0; r < 4; ++r) {
      int row = srow + r * 32;
      gload16(Ab + (size_t)(m0 + row) * K * 2 + scb, (char*)As + t * 16 + r * 4096);
    }
#pragma unroll
    for (int r = 0; r < 3; ++r) {
      int row = srow + r * 32;
      gload16(Bb + (size_t)(n0 + row) * K * 2 + scb, (char*)Bs + t * 16 + r * 4096);
    }
    __syncthreads();
#pragma unroll
    for (int kk = 0; kk < 2; ++kk) {
      bf16x8 af[4], bfr[3];
#pragma unroll
      for (int i = 0; i < 4; ++i)
        af[i] = *(const bf16x8*)&As[(wr + i * 16 + fr) * 64 + kk * 32 + fk];
#pragma unroll
      for (int j = 0; j < 3; ++j)
        bfr[j] = *(const bf16x8*)&Bs[(wc + j * 16 + fr) * 64 + kk * 32 + fk];
#pragma unroll
      for (int i = 0; i < 4; ++i)
#pragma unroll
        for (int j = 0; j < 3; ++j)
          acc[i][j] = __builtin_amdgcn_mfma_f32_16x16x32_bf16(af[i], bfr[j], acc[i][j], 0, 0, 0);
    }
    __syncthreads();
  }
  const int cr = (lane >> 4) * 4, cc = lane & 15;
#pragma unroll
  for (int i = 0; i < 4; ++i)
#pragma unroll
    for (int j = 0; j < 3; ++j) {
      const int row = m0 + wr + i * 16 + cr;
      const int col = n0 + wc + j * 16 + cc;
#pragma unroll
      for (int r = 0; r < 4; ++r) C[(size_t)(row + r) * N + col] = acc[i][j][r];
    }
}

// ------------- GEMM 256x256 body (single-buffered R7 schedule) -------------
__device__ __forceinline__ void stage_region(const u16* __restrict__ G, int ldk,
                                             int rowbase, int colbase,
                                             u16* lds, int t) {
  const int srow = t >> 2, sc = t & 3;
  const int swz = (srow >> 1) & 3;
#pragma unroll
  for (int r = 0; r < 2; ++r) {
    int row = r * 128 + srow;
    gload16(G + (size_t)(rowbase + row) * ldk + colbase + (sc ^ swz) * 8,
            (char*)lds + t * 16 + r * 8192);
  }
}

#define GPHASE(MSUB, KK, STAGE_STMT, RELOAD_B, VM0)                               \
  {                                                                               \
    STAGE_STMT;                                                                   \
    const u16* Aarr = (KK) ? A1s : A0s;                                           \
    _Pragma("unroll")                                                             \
    for (int fi = 0; fi < 4; ++fi) {                                              \
      int rowa = RM + (MSUB) * 64 + fi * 16 + fr;                                 \
      af[fi] = *(const bf16x8*)((const char*)Aarr + rowa * 64 +                   \
                                ((q ^ ((rowa >> 1) & 3)) * 16));                  \
    }                                                                             \
    if (RELOAD_B) {                                                               \
      const u16* Barr = (KK) ? B1s : B0s;                                         \
      _Pragma("unroll")                                                           \
      for (int j = 0; j < 4; ++j) {                                               \
        int rowb = RN + j * 16 + fr;                                              \
        bf[j] = *(const bf16x8*)((const char*)Barr + rowb * 64 +                  \
                                 ((q ^ ((rowb >> 1) & 3)) * 16));                 \
      }                                                                           \
    }                                                                             \
    if (VM0) { asm volatile("s_waitcnt vmcnt(0)" ::: "memory"); }                 \
    else     { asm volatile("s_waitcnt vmcnt(2)" ::: "memory"); }                 \
    __builtin_amdgcn_s_barrier();                                                 \
    asm volatile("s_waitcnt lgkmcnt(0)" ::: "memory");                            \
    __builtin_amdgcn_sched_barrier(0);                                            \
    __builtin_amdgcn_s_setprio(1);                                                \
    _Pragma("unroll")                                                             \
    for (int fi = 0; fi < 4; ++fi)                                                \
      _Pragma("unroll")                                                           \
      for (int j = 0; j < 4; ++j)                                                 \
        acc[(MSUB) * 4 + fi][j] = __builtin_amdgcn_mfma_f32_16x16x32_bf16(        \
            af[fi], bf[j], acc[(MSUB) * 4 + fi][j], 0, 0, 0);                     \
    __builtin_amdgcn_s_setprio(0);                                                \
    __builtin_amdgcn_s_barrier();                                                 \
  }

__device__ __forceinline__ void gemm256_body(
    const u16* __restrict__ A, const u16* __restrict__ Bt, u16* __restrict__ C,
    int N, int K, float scale, int bx, int by,
    u16* A0s, u16* A1s, u16* B0s, u16* B1s, int t) {
  const int lane = t & 63, wave = t >> 6;
  const int m0 = bx * 256, n0 = by * 256;
  const int RM = (wave >> 2) * 128, RN = (wave & 3) * 64;
  const int fr = lane & 15, q = lane >> 4;
  f32x4 acc[8][4];
#pragma unroll
  for (int i = 0; i < 8; ++i)
#pragma unroll
    for (int j = 0; j < 4; ++j)
#pragma unroll
      for (int r = 0; r < 4; ++r) acc[i][j][r] = 0.f;

  stage_region(Bt, K, n0, 0, B0s, t);
  stage_region(A, K, m0, 0, A0s, t);
  stage_region(Bt, K, n0, 32, B1s, t);
  asm volatile("s_waitcnt vmcnt(0)" ::: "memory");
  __builtin_amdgcn_s_barrier();

  const int nk = K >> 6;
#pragma unroll 1
  for (int kt = 0; kt < nk; ++kt) {
    const bool last = (kt == nk - 1);
    bf16x8 af[4], bf[4];
    GPHASE(0, 0, stage_region(A, K, m0, kt * 64 + 32, A1s, t), true, false)
    GPHASE(1, 0, if (!last) stage_region(Bt, K, n0, (kt + 1) * 64, B0s, t), false, last)
    GPHASE(1, 1, if (!last) stage_region(A, K, m0, (kt + 1) * 64, A0s, t), true, last)
    GPHASE(0, 1, if (!last) stage_region(Bt, K, n0, (kt + 1) * 64 + 32, B1s, t), false, last)
  }

  const int cr = (lane >> 4) * 4, cc = lane & 15;
#pragma unroll
  for (int i = 0; i < 8; ++i)
#pragma unroll
    for (int j = 0; j < 4; ++j) {
      const int row = m0 + RM + i * 16 + cr;
      const int col = n0 + RN + j * 16 + cc;
#pragma unroll
      for (int r = 0; r < 4; ++r) C[(size_t)(row + r) * N + col] = f2bf(acc[i][j][r] * scale);
    }
}

// merged k-GEMM + vt-GEMM with XCD-aware block placement (T1; FETCH 184->98MB).
__global__ __launch_bounds__(512) void gemm256_dual_kernel(
    const u16* __restrict__ xn, const u16* __restrict__ WkvT,
    u16* __restrict__ kb, u16* __restrict__ vtb, float kscale) {
  __shared__ __align__(16) u16 A0s[256 * 32];
  __shared__ __align__(16) u16 A1s[256 * 32];
  __shared__ __align__(16) u16 B0s[256 * 32];
  __shared__ __align__(16) u16 B1s[256 * 32];
  const int t = threadIdx.x;
  const int bid = blockIdx.x;
  const int l = (bid & 7) * 64 + (bid >> 3);  // bijective XCD-chunk remap
  if (l < 256) {
    const int g = l >> 6, r = l & 63;
    gemm256_body(xn, WkvT, kb, 2048, 2048, kscale,
                 g * 8 + (r & 7), r >> 3, A0s, A1s, B0s, B1s, t);
  } else {
    const int l2 = l - 256;
    const int g = l2 >> 6, r = l2 & 63;
    const int z = g >> 1;
    gemm256_body(WkvT + (size_t)2048 * 2048, xn + (size_t)z * 4096 * 2048,
                 vtb + (size_t)z * 2048 * 4096, 4096, 2048, 1.0f,
                 r & 7, (g & 1) * 8 + (r >> 3), A0s, A1s, B0s, B1s, t);
  }
}

// ------------- flash attention v4 (proven 86us): 32 q/wave, KV-split-2 -------------
#define KVB 128
__device__ __forceinline__ int swz4(int row) {
  return ((row & 15) ^ (((row >> 4) & 1) << 2)) << 4;
}

__device__ __forceinline__ void stage_kv(const u16* Kbase, const u16* Vbase,
                                         int kv0, char* ks, char* vs, int t) {
  const int col = (t & 15) * 16;
#pragma unroll
  for (int r = 0; r < 4; ++r) {
    int row = (t >> 4) + r * 32;
    gload16((const char*)(Kbase + (size_t)(kv0 + row) * INN) + (col ^ swz4(row)),
            ks + t * 16 + r * 8192);
  }
#pragma unroll
  for (int r = 0; r < 4; ++r) {
    int row = (t >> 4) + r * 32;
    gload16((const char*)(Vbase + (size_t)row * N1T + kv0) + (col ^ swz4(row)),
            vs + t * 16 + r * 8192);
  }
}

__global__ __launch_bounds__(512, 2) void attn_kernel(
    const u16* __restrict__ Q, const u16* __restrict__ Kb,
    const u16* __restrict__ Vt, float* __restrict__ Opart,
    float* __restrict__ ml) {
  __shared__ __align__(16) u16 Ks[2][KVB * 128];   // [key][d]
  __shared__ __align__(16) u16 Vs[2][128 * KVB];   // [d][key]
  const int t = threadIdx.x, lane = t & 63, wave = t >> 6;
  const int bid = blockIdx.x;
  const int xcd = bid & 7, idx = bid >> 3;
  const int bh = (xcd << 2) | (idx >> 3);
  const int sub = idx & 7;
  const int qt = sub >> 1, half = sub & 1;
  const int b = bh >> 4, h = bh & 15;
  const int q0 = qt * 256 + wave * 32;
  const int fr = lane & 15, quad = lane >> 4;
  const int fk = quad * 8;
  const int frp = fr + (fr & 12);  // perm row offset

  bf16x8 qf0[4], qf1[4];
  {
    const u16* qr0 = Q + (size_t)(b * N2T + q0 + fr) * INN + h * DH;
    const u16* qr1 = Q + (size_t)(b * N2T + q0 + 16 + fr) * INN + h * DH;
#pragma unroll
    for (int c = 0; c < 4; ++c) {
      qf0[c] = *(const bf16x8*)(qr0 + c * 32 + fk);
      qf1[c] = *(const bf16x8*)(qr1 + c * 32 + fk);
    }
  }

  float m_run[2] = {-1e30f, -1e30f}, l_run[2] = {0.f, 0.f};
  f32x4 oT[2][8];
#pragma unroll
  for (int f = 0; f < 2; ++f)
#pragma unroll
    for (int i = 0; i < 8; ++i)
#pragma unroll
      for (int r = 0; r < 4; ++r) oT[f][i][r] = 0.f;

  const u16* Kbase = Kb + (size_t)(b * N1T) * INN + h * DH;
  const u16* Vbase = Vt + ((size_t)b * INN + h * DH) * N1T;
  const int kvb = half * 2048;

  const int NT = 2048 / KVB;  // 16 tiles
  int cur = 0;
  stage_kv(Kbase, Vbase, kvb, (char*)&Ks[0][0], (char*)&Vs[0][0], t);
  for (int tile = 0; tile < NT; ++tile) {
    if (tile + 1 < NT) {
      stage_kv(Kbase, Vbase, kvb + (tile + 1) * KVB, (char*)&Ks[cur ^ 1][0],
               (char*)&Vs[cur ^ 1][0], t);
      asm volatile("s_waitcnt vmcnt(8)" ::: "memory");
    } else {
      asm volatile("s_waitcnt vmcnt(0)" ::: "memory");
    }
    __builtin_amdgcn_s_barrier();
    __builtin_amdgcn_sched_barrier(0);
    const char* KsC = (const char*)&Ks[cur][0];
    const char* VsC = (const char*)&Vs[cur][0];

    // S^T = K_perm @ Q^T for both q-frags, kf read ONCE per (ni,c)
    f32x4 sT[2][8];
    __builtin_amdgcn_s_setprio(1);
#pragma unroll
    for (int ni = 0; ni < 8; ++ni) {
#pragma unroll
      for (int r = 0; r < 4; ++r) { sT[0][ni][r] = 0.f; sT[1][ni][r] = 0.f; }
      const int rowa = (ni >> 1) * 32 + (ni & 1) * 4 + frp;
      const int sz = swz4(rowa);
#pragma unroll
      for (int c = 0; c < 4; ++c) {
        bf16x8 kf = *(const bf16x8*)(KsC + rowa * 256 + ((c * 64 + quad * 16) ^ sz));
        sT[0][ni] = __builtin_amdgcn_mfma_f32_16x16x32_bf16(kf, qf0[c], sT[0][ni], 0, 0, 0);
        sT[1][ni] = __builtin_amdgcn_mfma_f32_16x16x32_bf16(kf, qf1[c], sT[1][ni], 0, 0, 0);
      }
    }
    __builtin_amdgcn_s_setprio(0);
    // online softmax in log2 domain, per q-frag
    union { u32 w[4]; bf16x8 v; } pa[2][4];
#pragma unroll
    for (int f = 0; f < 2; ++f) {
      float mt = sT[f][0][0];
#pragma unroll
      for (int ni = 0; ni < 8; ++ni)
#pragma unroll
        for (int r = 0; r < 4; ++r) mt = fmaxf(mt, sT[f][ni][r]);
      mt = fmaxf(mt, __shfl_xor(mt, 16));
      mt = fmaxf(mt, __shfl_xor(mt, 32));
      if (!__all(mt <= m_run[f] + 10.f)) {
        float mnew = fmaxf(m_run[f], mt);
        float alpha = exp2_fast(m_run[f] - mnew);
        m_run[f] = mnew;
        l_run[f] *= alpha;
#pragma unroll
        for (int i = 0; i < 8; ++i)
#pragma unroll
          for (int r = 0; r < 4; ++r) oT[f][i][r] *= alpha;
      }
      float lt = 0.f;
#pragma unroll
      for (int ni = 0; ni < 8; ++ni)
#pragma unroll
        for (int r = 0; r < 4; ++r) {
          sT[f][ni][r] = exp2_fast(sT[f][ni][r] - m_run[f]);
          lt += sT[f][ni][r];
        }
      lt += __shfl_xor(lt, 16);
      lt += __shfl_xor(lt, 32);
      l_run[f] += lt;
#pragma unroll
      for (int kk = 0; kk < 4; ++kk) {
        pa[f][kk].w[0] = cvtpk(sT[f][kk * 2][0], sT[f][kk * 2][1]);
        pa[f][kk].w[1] = cvtpk(sT[f][kk * 2][2], sT[f][kk * 2][3]);
        pa[f][kk].w[2] = cvtpk(sT[f][kk * 2 + 1][0], sT[f][kk * 2 + 1][1]);
        pa[f][kk].w[3] = cvtpk(sT[f][kk * 2 + 1][2], sT[f][kk * 2 + 1][3]);
      }
    }
    // O^T += V^T @ P for both q-frags, vf read ONCE per (ni2,kk)
    __builtin_amdgcn_s_setprio(1);
#pragma unroll
    for (int ni2 = 0; ni2 < 8; ++ni2) {
      const int rowv = ni2 * 16 + fr;
      const int sz = swz4(rowv);
#pragma unroll
      for (int kk = 0; kk < 4; ++kk) {
        bf16x8 vf = *(const bf16x8*)(VsC + rowv * 256 + ((kk * 64 + quad * 16) ^ sz));
        oT[0][ni2] = __builtin_amdgcn_mfma_f32_16x16x32_bf16(vf, pa[0][kk].v, oT[0][ni2], 0, 0, 0);
        oT[1][ni2] = __builtin_amdgcn_mfma_f32_16x16x32_bf16(vf, pa[1][kk].v, oT[1][ni2], 0, 0, 0);
      }
    }
    __builtin_amdgcn_s_setprio(0);
    __builtin_amdgcn_sched_barrier(0);
    __builtin_amdgcn_s_barrier();
    cur ^= 1;
  }
  // write unnormalized partials: Opart[half][(b*1024+q)*16+h][128 d]
#pragma unroll
  for (int f = 0; f < 2; ++f) {
    const size_t row = (size_t)(b * N2T + q0 + f * 16 + fr) * 16 + h;
    float* op = Opart + ((size_t)half * 32768 + row) * 128 + quad * 4;
#pragma unroll
    for (int ni2 = 0; ni2 < 8; ++ni2) {
      float4 v4 = {oT[f][ni2][0], oT[f][ni2][1], oT[f][ni2][2], oT[f][ni2][3]};
      *(float4*)(op + ni2 * 16) = v4;
    }
    if (quad == 0) {
      float2 v2 = {m_run[f], l_run[f]};
      *(float2*)(ml + ((size_t)half * 32768 + row) * 2) = v2;
    }
  }
}

// ------------- combine: merge 2 kv-half partials -> ab bf16 -------------
__global__ __launch_bounds__(256) void combine2_kernel(
    const float* __restrict__ Opart, const float* __restrict__ ml,
    u16* __restrict__ ab) {
  const int tid = blockIdx.x * 256 + threadIdx.x;  // 1,048,576 total
  const int row = tid >> 5;
  const int c = tid & 31;
  float2 ml1 = *(const float2*)(ml + (size_t)row * 2);
  float2 ml2 = *(const float2*)(ml + ((size_t)32768 + row) * 2);
  float m = fmaxf(ml1.x, ml2.x);
  float w1 = exp2_fast(ml1.x - m), w2 = exp2_fast(ml2.x - m);
  float inv = 1.0f / (w1 * ml1.y + w2 * ml2.y);
  float4 o1 = *(const float4*)(Opart + (size_t)row * 128 + c * 4);
  float4 o2 = *(const float4*)(Opart + ((size_t)32768 + row) * 128 + c * 4);
  union { ushort4 v4; u16 hh[4]; } pk;
  pk.hh[0] = f2bf((w1 * o1.x + w2 * o2.x) * inv);
  pk.hh[1] = f2bf((w1 * o1.y + w2 * o2.y) * inv);
  pk.hh[2] = f2bf((w1 * o1.z + w2 * o2.z) * inv);
  pk.hh[3] = f2bf((w1 * o1.w + w2 * o2.w) * inv);
  *(ushort4*)(ab + (size_t)(row >> 4) * 2048 + (row & 15) * 128 + c * 4) = pk.v4;
}

extern "C" void kernel_launch(void* const* d_in, const int* in_sizes, int n_in,
                              void* d_out, int out_size, void* d_ws, size_t ws_size,
                              hipStream_t stream) {
  const float* x = (const float*)d_in[0];
  const float* latents = (const float*)d_in[1];
  const float* ln1g = (const float*)d_in[2];
  const float* ln1b = (const float*)d_in[3];
  const float* ln2g = (const float*)d_in[4];
  const float* ln2b = (const float*)d_in[5];
  const float* Wq = (const float*)d_in[6];
  const float* Wkv = (const float*)d_in[7];
  const float* Wout = (const float*)d_in[8];

  char* w = (char*)d_ws;
  u16* xn = (u16*)w;   w += (size_t)8192 * 2048 * 2;   // 32.0 MB
  u16* lnb = (u16*)w;  w += (size_t)2048 * 3072 * 2;   // 12.6 MB
  u16* WqT = (u16*)w;  w += (size_t)2048 * 3072 * 2;
  u16* WkvT = (u16*)w; w += (size_t)4096 * 2048 * 2;
  u16* WoT = (u16*)w;  w += (size_t)3072 * 2048 * 2;
  u16* qb = (u16*)w;   w += (size_t)2048 * 2048 * 2;
  u16* kb = (u16*)w;   w += (size_t)8192 * 2048 * 2;
  u16* vtb = (u16*)w;  w += (size_t)2 * 2048 * 4096 * 2;
  u16* ab = (u16*)w;   w += (size_t)2048 * 2048 * 2;
  // attention partials OVERLAY xn+lnb (both dead before attn runs):
  // opart 2*32768*128*4B = 33.55 MB + ml 0.5 MB < 44.6 MB ✓
  float* opart = (float*)d_ws;
  float* mlbuf = (float*)((char*)d_ws + 33554432);

  dim3 blk(256);
  // all 5 preprocessing jobs in ONE launch (15360 blocks; LN-x first)
  preproc_kernel<<<dim3(15360), blk, 0, stream>>>(
      x, ln1g, ln1b, xn, latents, ln2g, ln2b, lnb,
      Wq, WqT, Wkv, WkvT, Wout, WoT);

  const float scale = 0.29730177875068026f;            // 1/sqrt(sqrt(128))
  const float qscale = scale * 1.4426950408889634f;    // fold log2e into q
  gemm_bt_kernel<<<dim3(16, 16), blk, 0, stream>>>(
      lnb, WqT, qb, 2048, 2048, 3072, qscale);
  gemm256_dual_kernel<<<dim3(512), dim3(512), 0, stream>>>(
      xn, WkvT, kb, vtb, scale);
  attn_kernel<<<dim3(256), dim3(512), 0, stream>>>(qb, kb, vtb, opart, mlbuf);
  combine2_kernel<<<dim3(4096), blk, 0, stream>>>(opart, mlbuf, ab);
  // final GEMM: BN=96 -> grid 16x32 = 512 blocks = exactly 2/CU (balanced)
  gemm_bt96_kernel<<<dim3(16, 32), blk, 0, stream>>>(
      ab, WoT, (float*)d_out, 2048, 3072, 2048);
}